// Round 2
// baseline (364.241 us; speedup 1.0000x reference)
//
#include <hip/hip_runtime.h>
#include <hip/hip_bf16.h>

// ---------------------------------------------------------------------------
// GraphSAGE 2-layer forward, fp32.
//   h   = relu( mean_agg(x) @ W1_l + b1 + x @ W1_r )
//   out =       mean_agg(h) @ W2_l + b2 + h @ W2_r
// Restructured: agg(x)@W = agg(x@W)  (segment-mean commutes with right-mul).
// Pipeline: CSR build -> p=x@W1_l, q=x@W1_r -> agg+relu -> g=h@W2_l, r=h@W2_r
//           -> agg+add.
// ---------------------------------------------------------------------------

#define N_NODES 50000
#define N_EDGES 800000

// ---------------- CSR build ----------------

__global__ __launch_bounds__(256) void count_kernel(const int* __restrict__ dst,
                                                    int* __restrict__ cnt, int E) {
    int e = blockIdx.x * 256 + threadIdx.x;
    if (e < E) atomicAdd(&cnt[dst[e]], 1);
}

// per-256-block exclusive scan; bsum[b] = block total
__global__ __launch_bounds__(256) void scan_blocks_kernel(const int* __restrict__ cnt,
                                                          int* __restrict__ row_start,
                                                          int* __restrict__ bsum, int N) {
    __shared__ int lds[256];
    int i = blockIdx.x * 256 + threadIdx.x;
    int v = (i < N) ? cnt[i] : 0;
    lds[threadIdx.x] = v;
    __syncthreads();
    for (int off = 1; off < 256; off <<= 1) {
        int t = (threadIdx.x >= off) ? lds[threadIdx.x - off] : 0;
        __syncthreads();
        lds[threadIdx.x] += t;
        __syncthreads();
    }
    if (i < N) row_start[i] = lds[threadIdx.x] - v;   // local exclusive
    if (threadIdx.x == 255) bsum[blockIdx.x] = lds[255];
}

// single block: exclusive scan of bsum (nb <= 256), total -> row_start[N]
__global__ __launch_bounds__(256) void scan_bsum_kernel(int* __restrict__ bsum,
                                                        int* __restrict__ row_start,
                                                        int nb, int N) {
    __shared__ int lds[256];
    int v = (threadIdx.x < nb) ? bsum[threadIdx.x] : 0;
    lds[threadIdx.x] = v;
    __syncthreads();
    for (int off = 1; off < 256; off <<= 1) {
        int t = (threadIdx.x >= off) ? lds[threadIdx.x - off] : 0;
        __syncthreads();
        lds[threadIdx.x] += t;
        __syncthreads();
    }
    if (threadIdx.x < nb) bsum[threadIdx.x] = lds[threadIdx.x] - v;  // exclusive
    if (threadIdx.x == 255) row_start[N] = lds[255];                 // grand total
}

__global__ __launch_bounds__(256) void add_off_kernel(int* __restrict__ row_start,
                                                      const int* __restrict__ bsum, int N) {
    int i = blockIdx.x * 256 + threadIdx.x;
    if (i < N) row_start[i] += bsum[i >> 8];
}

__global__ __launch_bounds__(256) void scatter_kernel(const int* __restrict__ src,
                                                      const int* __restrict__ dst,
                                                      const int* __restrict__ row_start,
                                                      int* __restrict__ cursor,
                                                      int* __restrict__ csr_src, int E) {
    int e = blockIdx.x * 256 + threadIdx.x;
    if (e < E) {
        int d = dst[e];
        int pos = atomicAdd(&cursor[d], 1);
        csr_src[row_start[d] + pos] = src[e];
    }
}

// ---------------- fp32 GEMM: C[M,BN] = A[M,128] @ W[128,BN] ----------------
// BN=128: BM=64,  thread grid 16x16 (colg x rowg), 4 rows x 8 cols each
// BN=64 : BM=128, thread grid  8x32,               4 rows x 8 cols each

template <int BN>
__global__ __launch_bounds__(256) void gemm_kernel(const float* __restrict__ A,
                                                   const float* __restrict__ W,
                                                   float* __restrict__ C, int M) {
    constexpr int K  = 128;
    constexpr int CG = BN / 8;        // col groups
    constexpr int RG = 256 / CG;      // row groups
    constexpr int BM = RG * 4;
    constexpr int BK = 32;

    __shared__ float sA[BM][BK + 4];  // +4 floats: rows stay 16B-aligned
    __shared__ float sW[BK][BN];

    const int t   = threadIdx.x;
    const int cg  = t % CG;
    const int rg  = t / CG;
    const int row0 = blockIdx.x * BM;

    float acc[4][8] = {};

    for (int k0 = 0; k0 < K; k0 += BK) {
        // A tile: BM x 32 floats, float4 loads (BM*8 float4s)
        for (int idx = t; idx < BM * 8; idx += 256) {
            int r = idx >> 3, c4 = idx & 7;
            int gr = row0 + r;
            float4 v = make_float4(0.f, 0.f, 0.f, 0.f);
            if (gr < M) v = *(const float4*)(A + (size_t)gr * K + k0 + c4 * 4);
            *(float4*)&sA[r][c4 * 4] = v;
        }
        // W tile: BK x BN floats = 8*BN float4s   (was 4*BN: half-tile bug)
        for (int idx = t; idx < 8 * BN; idx += 256) {
            int r = idx / (BN / 4), c4 = idx % (BN / 4);
            *(float4*)&sW[r][c4 * 4] = *(const float4*)(W + (size_t)(k0 + r) * BN + c4 * 4);
        }
        __syncthreads();

        for (int kk = 0; kk < BK; ++kk) {
            float a[4], b[8];
#pragma unroll
            for (int i = 0; i < 4; ++i) a[i] = sA[rg * 4 + i][kk];
#pragma unroll
            for (int j = 0; j < 8; ++j) b[j] = sW[kk][cg * 8 + j];
#pragma unroll
            for (int i = 0; i < 4; ++i)
#pragma unroll
                for (int j = 0; j < 8; ++j) acc[i][j] = fmaf(a[i], b[j], acc[i][j]);
        }
        __syncthreads();
    }

    for (int i = 0; i < 4; ++i) {
        int gr = row0 + rg * 4 + i;
        if (gr < M) {
            float4* d = (float4*)(C + (size_t)gr * BN + cg * 8);
            d[0] = make_float4(acc[i][0], acc[i][1], acc[i][2], acc[i][3]);
            d[1] = make_float4(acc[i][4], acc[i][5], acc[i][6], acc[i][7]);
        }
    }
}

// ---------------- aggregation ----------------
// layer 1: h[n] = relu( (sum_{s in in(n)} p[s]) / max(deg,1) + q[n] + b1 )
__global__ __launch_bounds__(256) void agg1_kernel(const float* __restrict__ p,
                                                   const float* __restrict__ q,
                                                   const float* __restrict__ b1,
                                                   const int* __restrict__ row_start,
                                                   const int* __restrict__ csr_src,
                                                   float* __restrict__ h, int N) {
    int wave = threadIdx.x >> 6;
    int lane = threadIdx.x & 63;
    int n = blockIdx.x * 4 + wave;
    if (n >= N) return;
    int s0 = row_start[n], s1 = row_start[n + 1];
    float ax = 0.f, ay = 0.f;
    for (int e = s0; e < s1; ++e) {
        int s = csr_src[e];
        float2 v = *(const float2*)(p + (size_t)s * 128 + lane * 2);
        ax += v.x; ay += v.y;
    }
    float inv = 1.0f / (float)max(s1 - s0, 1);
    float2 qq = *(const float2*)(q + (size_t)n * 128 + lane * 2);
    float2 bb = *(const float2*)(b1 + lane * 2);
    float hx = fmaxf(fmaf(ax, inv, qq.x + bb.x), 0.0f);
    float hy = fmaxf(fmaf(ay, inv, qq.y + bb.y), 0.0f);
    *(float2*)(h + (size_t)n * 128 + lane * 2) = make_float2(hx, hy);
}

// layer 2: out[n] = (sum g[s]) / max(deg,1) + r[n] + b2
__global__ __launch_bounds__(256) void agg2_kernel(const float* __restrict__ g,
                                                   const float* __restrict__ r,
                                                   const float* __restrict__ b2,
                                                   const int* __restrict__ row_start,
                                                   const int* __restrict__ csr_src,
                                                   float* __restrict__ out, int N) {
    int wave = threadIdx.x >> 6;
    int lane = threadIdx.x & 63;
    int n = blockIdx.x * 4 + wave;
    if (n >= N) return;
    int s0 = row_start[n], s1 = row_start[n + 1];
    float acc = 0.f;
    for (int e = s0; e < s1; ++e) {
        int s = csr_src[e];
        acc += g[(size_t)s * 64 + lane];
    }
    float inv = 1.0f / (float)max(s1 - s0, 1);
    out[(size_t)n * 64 + lane] = fmaf(acc, inv, r[(size_t)n * 64 + lane] + b2[lane]);
}

// ---------------------------------------------------------------------------

extern "C" void kernel_launch(void* const* d_in, const int* in_sizes, int n_in,
                              void* d_out, int out_size, void* d_ws, size_t ws_size,
                              hipStream_t stream) {
    const float* x    = (const float*)d_in[0];
    const int*   ei   = (const int*)d_in[1];
    const float* W1_l = (const float*)d_in[2];
    const float* b1   = (const float*)d_in[3];
    const float* W1_r = (const float*)d_in[4];
    const float* W2_l = (const float*)d_in[5];
    const float* b2   = (const float*)d_in[6];
    const float* W2_r = (const float*)d_in[7];

    const int N = in_sizes[0] / 128;      // 50000
    const int E = in_sizes[1] / 2;        // 800000
    const int* e_src = ei;
    const int* e_dst = ei + E;

    // ---- workspace layout (256B-aligned regions) ----
    char* ws = (char*)d_ws;
    auto align256 = [](size_t v) { return (v + 255) & ~(size_t)255; };
    size_t off = 0;
    int* row_start = (int*)(ws + off); off += align256((size_t)(N + 1) * 4);
    int* cnt       = (int*)(ws + off); off += align256((size_t)N * 4);
    int* cursor    = (int*)(ws + off); off += align256((size_t)N * 4);
    int* bsum      = (int*)(ws + off); off += align256(1024);
    int* csr_src   = (int*)(ws + off); off += align256((size_t)E * 4);
    float* p       = (float*)(ws + off); off += align256((size_t)N * 128 * 4);
    float* q       = (float*)(ws + off); off += align256((size_t)N * 128 * 4);
    float* h       = (float*)(ws + off); off += align256((size_t)N * 128 * 4);
    float* g       = p;   // reuse after h is built (N*64 <= N*128)
    float* r       = q;
    float* out     = (float*)d_out;

    // ---- CSR build ----
    hipMemsetAsync(cnt, 0, (size_t)N * 4, stream);
    hipMemsetAsync(cursor, 0, (size_t)N * 4, stream);
    count_kernel<<<(E + 255) / 256, 256, 0, stream>>>(e_dst, cnt, E);
    const int nb = (N + 255) / 256;
    scan_blocks_kernel<<<nb, 256, 0, stream>>>(cnt, row_start, bsum, N);
    scan_bsum_kernel<<<1, 256, 0, stream>>>(bsum, row_start, nb, N);
    add_off_kernel<<<nb, 256, 0, stream>>>(row_start, bsum, N);
    scatter_kernel<<<(E + 255) / 256, 256, 0, stream>>>(e_src, e_dst, row_start,
                                                        cursor, csr_src, E);

    // ---- layer 1 ----
    gemm_kernel<128><<<(N + 63) / 64, 256, 0, stream>>>(x, W1_l, p, N);
    gemm_kernel<128><<<(N + 63) / 64, 256, 0, stream>>>(x, W1_r, q, N);
    agg1_kernel<<<(N + 3) / 4, 256, 0, stream>>>(p, q, b1, row_start, csr_src, h, N);

    // ---- layer 2 ----
    gemm_kernel<64><<<(N + 127) / 128, 256, 0, stream>>>(h, W2_l, g, N);
    gemm_kernel<64><<<(N + 127) / 128, 256, 0, stream>>>(h, W2_r, r, N);
    agg2_kernel<<<(N + 3) / 4, 256, 0, stream>>>(g, r, b2, row_start, csr_src, out, N);
}

// Round 3
// 270.745 us; speedup vs baseline: 1.3453x; 1.3453x over previous
//
#include <hip/hip_runtime.h>
#include <hip/hip_bf16.h>

// ---------------------------------------------------------------------------
// GraphSAGE 2-layer forward.
//   h   = relu( mean_agg(x) @ W1_l + b1 + x @ W1_r )
//   out =       mean_agg(h) @ W2_l + b2 + h @ W2_r
// agg(x)@W == agg(x@W): transform-then-aggregate.
// bf16 for MFMA operands (x,h) and gather buffers (p,g); fp32 for q,r,out.
// Pipeline: CSR build | x->bf16, W->W^T bf16 | MFMA dual-GEMM (p bf16, q f32)
//           | agg1 -> h bf16 | MFMA dual-GEMM (g bf16, r f32) | agg2 -> out.
// ---------------------------------------------------------------------------

typedef __attribute__((ext_vector_type(8))) short bf16x8;
typedef __attribute__((ext_vector_type(4))) float f32x4;

__device__ __forceinline__ float bf_lo(unsigned u) {
    u <<= 16; return __builtin_bit_cast(float, u);
}
__device__ __forceinline__ float bf_hi(unsigned u) {
    u &= 0xffff0000u; return __builtin_bit_cast(float, u);
}
__device__ __forceinline__ unsigned short f2bf(float f) {
    __hip_bfloat16 b = __float2bfloat16(f);
    return __builtin_bit_cast(unsigned short, b);
}

// ---------------- CSR build ----------------

__global__ __launch_bounds__(256) void count_kernel(const int* __restrict__ dst,
                                                    int* __restrict__ cnt, int E) {
    int e = blockIdx.x * 256 + threadIdx.x;
    if (e < E) atomicAdd(&cnt[dst[e]], 1);
}

__global__ __launch_bounds__(256) void scan_blocks_kernel(const int* __restrict__ cnt,
                                                          int* __restrict__ row_start,
                                                          int* __restrict__ bsum, int N) {
    __shared__ int lds[256];
    int i = blockIdx.x * 256 + threadIdx.x;
    int v = (i < N) ? cnt[i] : 0;
    lds[threadIdx.x] = v;
    __syncthreads();
    for (int off = 1; off < 256; off <<= 1) {
        int t = (threadIdx.x >= off) ? lds[threadIdx.x - off] : 0;
        __syncthreads();
        lds[threadIdx.x] += t;
        __syncthreads();
    }
    if (i < N) row_start[i] = lds[threadIdx.x] - v;
    if (threadIdx.x == 255) bsum[blockIdx.x] = lds[255];
}

__global__ __launch_bounds__(256) void scan_bsum_kernel(int* __restrict__ bsum,
                                                        int* __restrict__ row_start,
                                                        int nb, int N) {
    __shared__ int lds[256];
    int v = (threadIdx.x < nb) ? bsum[threadIdx.x] : 0;
    lds[threadIdx.x] = v;
    __syncthreads();
    for (int off = 1; off < 256; off <<= 1) {
        int t = (threadIdx.x >= off) ? lds[threadIdx.x - off] : 0;
        __syncthreads();
        lds[threadIdx.x] += t;
        __syncthreads();
    }
    if (threadIdx.x < nb) bsum[threadIdx.x] = lds[threadIdx.x] - v;
    if (threadIdx.x == 255) row_start[N] = lds[255];
}

__global__ __launch_bounds__(256) void add_off_kernel(int* __restrict__ row_start,
                                                      const int* __restrict__ bsum, int N) {
    int i = blockIdx.x * 256 + threadIdx.x;
    if (i < N) row_start[i] += bsum[i >> 8];
}

__global__ __launch_bounds__(256) void scatter_kernel(const int* __restrict__ src,
                                                      const int* __restrict__ dst,
                                                      const int* __restrict__ row_start,
                                                      int* __restrict__ cursor,
                                                      int* __restrict__ csr_src, int E) {
    int e = blockIdx.x * 256 + threadIdx.x;
    if (e < E) {
        int d = dst[e];
        int pos = atomicAdd(&cursor[d], 1);
        csr_src[row_start[d] + pos] = src[e];
    }
}

// ---------------- dtype prep ----------------

// f32 -> bf16, n multiple of 4
__global__ __launch_bounds__(256) void f2bf_kernel(const float* __restrict__ in,
                                                   unsigned short* __restrict__ out, int n4) {
    int i = blockIdx.x * 256 + threadIdx.x;
    if (i < n4) {
        float4 v = *(const float4*)(in + (size_t)i * 4);
        ushort4 o;
        o.x = f2bf(v.x); o.y = f2bf(v.y); o.z = f2bf(v.z); o.w = f2bf(v.w);
        *(ushort4*)(out + (size_t)i * 4) = o;
    }
}

// W[K][N] f32 -> WT[N][K] bf16
__global__ __launch_bounds__(256) void wt_kernel(const float* __restrict__ W,
                                                 unsigned short* __restrict__ WT,
                                                 int K, int N) {
    int i = blockIdx.x * 256 + threadIdx.x;
    if (i < K * N) {
        int k = i / N, n = i % N;
        WT[(size_t)n * K + k] = f2bf(W[i]);
    }
}

// ---------------- MFMA dual GEMM ----------------
// A[M][128] bf16 row-major; WTl/WTr[NC][128] bf16 (= W^T).
// Pl = A@Wl as bf16, Qr = A@Wr as f32. One wave = 16 output rows.
// mfma_f32_16x16x32_bf16: A-frag lane l -> row l&15, k = (l>>4)*8+j;
// B-frag lane l -> col l&15, k = (l>>4)*8+j; D: col=lane&15, row=(lane>>4)*4+reg.

template <int NC>
__global__ __launch_bounds__(256) void mfma_dual_gemm(
    const unsigned short* __restrict__ A,
    const unsigned short* __restrict__ WTl,
    const unsigned short* __restrict__ WTr,
    unsigned short* __restrict__ Pl,
    float* __restrict__ Qr, int M) {
    const int wave = threadIdx.x >> 6;
    const int lane = threadIdx.x & 63;
    const int m0 = blockIdx.x * 64 + wave * 16;
    const int lr = lane & 15;    // row (A) / col (B) within tile
    const int lk = lane >> 4;    // k-group

    int arow = m0 + lr;
    if (arow >= M) arow = M - 1;
    const unsigned short* Ab = A + (size_t)arow * 128 + lk * 8;

    bf16x8 af[4];
#pragma unroll
    for (int s = 0; s < 4; ++s) af[s] = *(const bf16x8*)(Ab + s * 32);

#pragma unroll
    for (int ct = 0; ct < NC / 16; ++ct) {
        const unsigned short* Bl = WTl + (size_t)(ct * 16 + lr) * 128 + lk * 8;
        const unsigned short* Br = WTr + (size_t)(ct * 16 + lr) * 128 + lk * 8;
        f32x4 accL = {0.f, 0.f, 0.f, 0.f};
        f32x4 accR = {0.f, 0.f, 0.f, 0.f};
#pragma unroll
        for (int s = 0; s < 4; ++s) {
            bf16x8 bl = *(const bf16x8*)(Bl + s * 32);
            bf16x8 br = *(const bf16x8*)(Br + s * 32);
            accL = __builtin_amdgcn_mfma_f32_16x16x32_bf16(af[s], bl, accL, 0, 0, 0);
            accR = __builtin_amdgcn_mfma_f32_16x16x32_bf16(af[s], br, accR, 0, 0, 0);
        }
#pragma unroll
        for (int r = 0; r < 4; ++r) {
            int gr = m0 + lk * 4 + r;
            if (gr < M) {
                Pl[(size_t)gr * NC + ct * 16 + lr] = f2bf(accL[r]);
                Qr[(size_t)gr * NC + ct * 16 + lr] = accR[r];
            }
        }
    }
}

// ---------------- aggregation ----------------
// layer 1: h[n] = relu( mean(p[src]) + q[n] + b1 ), p/h bf16, q f32.
__global__ __launch_bounds__(256) void agg1_kernel(const unsigned short* __restrict__ p,
                                                   const float* __restrict__ q,
                                                   const float* __restrict__ b1,
                                                   const int* __restrict__ row_start,
                                                   const int* __restrict__ csr_src,
                                                   unsigned short* __restrict__ h, int N) {
    int wave = threadIdx.x >> 6;
    int lane = threadIdx.x & 63;
    int n = blockIdx.x * 4 + wave;
    if (n >= N) return;
    int s0 = row_start[n], s1 = row_start[n + 1];
    float ax = 0.f, ay = 0.f, bx = 0.f, by = 0.f;
    int e = s0;
    for (; e + 1 < s1; e += 2) {
        unsigned u0 = *(const unsigned*)(p + (size_t)csr_src[e] * 128 + lane * 2);
        unsigned u1 = *(const unsigned*)(p + (size_t)csr_src[e + 1] * 128 + lane * 2);
        ax += bf_lo(u0); ay += bf_hi(u0);
        bx += bf_lo(u1); by += bf_hi(u1);
    }
    if (e < s1) {
        unsigned u0 = *(const unsigned*)(p + (size_t)csr_src[e] * 128 + lane * 2);
        ax += bf_lo(u0); ay += bf_hi(u0);
    }
    float sx = ax + bx, sy = ay + by;
    float inv = 1.0f / (float)max(s1 - s0, 1);
    float2 qq = *(const float2*)(q + (size_t)n * 128 + lane * 2);
    float2 bb = *(const float2*)(b1 + lane * 2);
    float hx = fmaxf(fmaf(sx, inv, qq.x + bb.x), 0.0f);
    float hy = fmaxf(fmaf(sy, inv, qq.y + bb.y), 0.0f);
    ushort2 o; o.x = f2bf(hx); o.y = f2bf(hy);
    *(ushort2*)(h + (size_t)n * 128 + lane * 2) = o;
}

// layer 2: out[n] = mean(g[src]) + r[n] + b2, g bf16, r/out f32, 64 ch.
__global__ __launch_bounds__(256) void agg2_kernel(const unsigned short* __restrict__ g,
                                                   const float* __restrict__ r,
                                                   const float* __restrict__ b2,
                                                   const int* __restrict__ row_start,
                                                   const int* __restrict__ csr_src,
                                                   float* __restrict__ out, int N) {
    int wave = threadIdx.x >> 6;
    int lane = threadIdx.x & 63;
    int n = blockIdx.x * 4 + wave;
    if (n >= N) return;
    int s0 = row_start[n], s1 = row_start[n + 1];
    float a0 = 0.f, a1 = 0.f;
    int e = s0;
    for (; e + 1 < s1; e += 2) {
        unsigned short u0 = g[(size_t)csr_src[e] * 64 + lane];
        unsigned short u1 = g[(size_t)csr_src[e + 1] * 64 + lane];
        a0 += bf_lo((unsigned)u0 << 16 >> 16 | ((unsigned)u0 << 16));  // placeholder avoided below
        a1 += 0.f;
        // (see simplified scalar path below)
        (void)u1;
        break;  // never taken; real loop below
    }
    // simple scalar loop (kept branch-free per edge)
    a0 = 0.f; a1 = 0.f;
    for (e = s0; e + 1 < s1; e += 2) {
        unsigned v0 = (unsigned)g[(size_t)csr_src[e] * 64 + lane] << 16;
        unsigned v1 = (unsigned)g[(size_t)csr_src[e + 1] * 64 + lane] << 16;
        a0 += __builtin_bit_cast(float, v0);
        a1 += __builtin_bit_cast(float, v1);
    }
    if (e < s1) {
        unsigned v0 = (unsigned)g[(size_t)csr_src[e] * 64 + lane] << 16;
        a0 += __builtin_bit_cast(float, v0);
    }
    float inv = 1.0f / (float)max(s1 - s0, 1);
    out[(size_t)n * 64 + lane] = fmaf(a0 + a1, inv, r[(size_t)n * 64 + lane] + b2[lane]);
}

// ---------------------------------------------------------------------------

extern "C" void kernel_launch(void* const* d_in, const int* in_sizes, int n_in,
                              void* d_out, int out_size, void* d_ws, size_t ws_size,
                              hipStream_t stream) {
    const float* x    = (const float*)d_in[0];
    const int*   ei   = (const int*)d_in[1];
    const float* W1_l = (const float*)d_in[2];
    const float* b1   = (const float*)d_in[3];
    const float* W1_r = (const float*)d_in[4];
    const float* W2_l = (const float*)d_in[5];
    const float* b2   = (const float*)d_in[6];
    const float* W2_r = (const float*)d_in[7];

    const int N = in_sizes[0] / 128;   // 50000
    const int E = in_sizes[1] / 2;     // 800000
    const int* e_src = ei;
    const int* e_dst = ei + E;

    // ---- workspace layout ----
    char* ws = (char*)d_ws;
    auto align256 = [](size_t v) { return (v + 255) & ~(size_t)255; };
    size_t off = 0;
    int* row_start = (int*)(ws + off); off += align256((size_t)(N + 1) * 4);
    int* cnt       = (int*)(ws + off); off += align256((size_t)N * 4);
    int* cursor    = (int*)(ws + off); off += align256((size_t)N * 4);
    int* bsum      = (int*)(ws + off); off += align256(1024);
    int* csr_src   = (int*)(ws + off); off += align256((size_t)E * 4);
    unsigned short* xh_bf = (unsigned short*)(ws + off); off += align256((size_t)N * 128 * 2); // x, then h
    unsigned short* pg_bf = (unsigned short*)(ws + off); off += align256((size_t)N * 128 * 2); // p, then g
    float* qr_f32         = (float*)(ws + off);          off += align256((size_t)N * 128 * 4); // q, then r
    unsigned short* wt1l  = (unsigned short*)(ws + off); off += align256(128 * 128 * 2);
    unsigned short* wt1r  = (unsigned short*)(ws + off); off += align256(128 * 128 * 2);
    unsigned short* wt2l  = (unsigned short*)(ws + off); off += align256(128 * 64 * 2);
    unsigned short* wt2r  = (unsigned short*)(ws + off); off += align256(128 * 64 * 2);
    float* out = (float*)d_out;

    // ---- CSR build ----
    hipMemsetAsync(cnt, 0, (size_t)N * 4, stream);
    hipMemsetAsync(cursor, 0, (size_t)N * 4, stream);
    count_kernel<<<(E + 255) / 256, 256, 0, stream>>>(e_dst, cnt, E);
    const int nb = (N + 255) / 256;
    scan_blocks_kernel<<<nb, 256, 0, stream>>>(cnt, row_start, bsum, N);
    scan_bsum_kernel<<<1, 256, 0, stream>>>(bsum, row_start, nb, N);
    add_off_kernel<<<nb, 256, 0, stream>>>(row_start, bsum, N);
    scatter_kernel<<<(E + 255) / 256, 256, 0, stream>>>(e_src, e_dst, row_start,
                                                        cursor, csr_src, E);

    // ---- dtype prep ----
    f2bf_kernel<<<(N * 128 / 4 + 255) / 256, 256, 0, stream>>>(x, xh_bf, N * 128 / 4);
    wt_kernel<<<(128 * 128 + 255) / 256, 256, 0, stream>>>(W1_l, wt1l, 128, 128);
    wt_kernel<<<(128 * 128 + 255) / 256, 256, 0, stream>>>(W1_r, wt1r, 128, 128);
    wt_kernel<<<(128 * 64 + 255) / 256, 256, 0, stream>>>(W2_l, wt2l, 128, 64);
    wt_kernel<<<(128 * 64 + 255) / 256, 256, 0, stream>>>(W2_r, wt2r, 128, 64);

    // ---- layer 1: p = x@W1_l (bf16), q = x@W1_r (f32) ----
    mfma_dual_gemm<128><<<(N + 63) / 64, 256, 0, stream>>>(xh_bf, wt1l, wt1r,
                                                           pg_bf, qr_f32, N);
    agg1_kernel<<<(N + 3) / 4, 256, 0, stream>>>(pg_bf, qr_f32, b1, row_start,
                                                 csr_src, xh_bf, N);  // h -> xh_bf

    // ---- layer 2: g = h@W2_l (bf16), r = h@W2_r (f32) ----
    mfma_dual_gemm<64><<<(N + 63) / 64, 256, 0, stream>>>(xh_bf, wt2l, wt2r,
                                                          pg_bf, qr_f32, N);
    agg2_kernel<<<(N + 3) / 4, 256, 0, stream>>>(pg_bf, qr_f32, b2, row_start,
                                                 csr_src, out, N);
}

// Round 4
// 226.444 us; speedup vs baseline: 1.6085x; 1.1956x over previous
//
#include <hip/hip_runtime.h>
#include <hip/hip_bf16.h>

// ---------------------------------------------------------------------------
// GraphSAGE 2-layer forward.
//   h   = relu( mean_agg(x) @ W1_l + b1 + x @ W1_r )
//   out =       mean_agg(h) @ W2_l + b2 + h @ W2_r
// agg(x)@W == agg(x@W): transform-then-aggregate.
// bf16 MFMA GEMMs; bf16 gather buffers (p,g); fp32 addends (q,r) and out.
// CSR build uses XCD-sliced commit: chunk c is processed by the 8 WGs
// [8c, 8c+8); WG with blockIdx&7==j commits only dst in node-slice j, so
// (under round-robin WG->XCD dispatch) each slice's cnt/cursor/csr lines are
// written from a single XCD -> no cross-XCD line ping-pong. Correct under any
// placement: slices partition nodes, each edge committed exactly once.
// ---------------------------------------------------------------------------

typedef __attribute__((ext_vector_type(8))) short bf16x8;
typedef __attribute__((ext_vector_type(4))) float f32x4;

static __device__ __forceinline__ float bf_lo(unsigned u) {
    u <<= 16; return __builtin_bit_cast(float, u);
}
static __device__ __forceinline__ float bf_hi(unsigned u) {
    u &= 0xffff0000u; return __builtin_bit_cast(float, u);
}
static __device__ __forceinline__ unsigned short f2bf(float f) {
    __hip_bfloat16 b = __float2bfloat16(f);
    return __builtin_bit_cast(unsigned short, b);
}

#define CSR_CHUNK 4096

// ---------------- CSR build (XCD-sliced) ----------------

__global__ __launch_bounds__(256) void count_sliced_kernel(const int* __restrict__ dst,
                                                           int* __restrict__ cnt,
                                                           int E, int N) {
    const int j = blockIdx.x & 7;
    const int chunk = blockIdx.x >> 3;
    const int sliceW = (N + 7) >> 3;
    const int lo = j * sliceW;
    const int hi = min(N, lo + sliceW);
    const int base = chunk * CSR_CHUNK;
    const int end = min(E, base + CSR_CHUNK);
    for (int e = base + threadIdx.x; e < end; e += 256) {
        int d = dst[e];
        if (d >= lo && d < hi) atomicAdd(&cnt[d], 1);
    }
}

__global__ __launch_bounds__(256) void scan_blocks_kernel(const int* __restrict__ cnt,
                                                          int* __restrict__ row_start,
                                                          int* __restrict__ bsum, int N) {
    __shared__ int lds[256];
    int i = blockIdx.x * 256 + threadIdx.x;
    int v = (i < N) ? cnt[i] : 0;
    lds[threadIdx.x] = v;
    __syncthreads();
    for (int off = 1; off < 256; off <<= 1) {
        int t = (threadIdx.x >= off) ? lds[threadIdx.x - off] : 0;
        __syncthreads();
        lds[threadIdx.x] += t;
        __syncthreads();
    }
    if (i < N) row_start[i] = lds[threadIdx.x] - v;
    if (threadIdx.x == 255) bsum[blockIdx.x] = lds[255];
}

__global__ __launch_bounds__(256) void scan_bsum_kernel(int* __restrict__ bsum,
                                                        int* __restrict__ row_start,
                                                        int nb, int N) {
    __shared__ int lds[256];
    int v = (threadIdx.x < nb) ? bsum[threadIdx.x] : 0;
    lds[threadIdx.x] = v;
    __syncthreads();
    for (int off = 1; off < 256; off <<= 1) {
        int t = (threadIdx.x >= off) ? lds[threadIdx.x - off] : 0;
        __syncthreads();
        lds[threadIdx.x] += t;
        __syncthreads();
    }
    if (threadIdx.x < nb) bsum[threadIdx.x] = lds[threadIdx.x] - v;
    if (threadIdx.x == 255) row_start[N] = lds[255];
}

__global__ __launch_bounds__(256) void add_off_kernel(int* __restrict__ row_start,
                                                      const int* __restrict__ bsum, int N) {
    int i = blockIdx.x * 256 + threadIdx.x;
    if (i < N) row_start[i] += bsum[i >> 8];
}

__global__ __launch_bounds__(256) void scatter_sliced_kernel(const int* __restrict__ src,
                                                             const int* __restrict__ dst,
                                                             const int* __restrict__ row_start,
                                                             int* __restrict__ cursor,
                                                             int* __restrict__ csr_src,
                                                             int E, int N) {
    const int j = blockIdx.x & 7;
    const int chunk = blockIdx.x >> 3;
    const int sliceW = (N + 7) >> 3;
    const int lo = j * sliceW;
    const int hi = min(N, lo + sliceW);
    const int base = chunk * CSR_CHUNK;
    const int end = min(E, base + CSR_CHUNK);
    for (int e = base + threadIdx.x; e < end; e += 256) {
        int d = dst[e];
        if (d >= lo && d < hi) {
            int pos = atomicAdd(&cursor[d], 1);
            csr_src[row_start[d] + pos] = src[e];
        }
    }
}

// ---------------- weight prep: 4 transposes in one launch ----------------
// W[K][N] f32 -> WT[N][K] bf16 for (W1_l, W1_r: 128x128) (W2_l, W2_r: 128x64)

__global__ __launch_bounds__(256) void wt_all_kernel(const float* __restrict__ W1l,
                                                     const float* __restrict__ W1r,
                                                     const float* __restrict__ W2l,
                                                     const float* __restrict__ W2r,
                                                     unsigned short* __restrict__ T1l,
                                                     unsigned short* __restrict__ T1r,
                                                     unsigned short* __restrict__ T2l,
                                                     unsigned short* __restrict__ T2r) {
    int i = blockIdx.x * 256 + threadIdx.x;   // grid covers 2*16384 + 2*8192
    if (i < 16384) {
        int k = i >> 7, n = i & 127;
        T1l[n * 128 + k] = f2bf(W1l[i]);
        T1r[n * 128 + k] = f2bf(W1r[i]);
    } else if (i < 16384 + 8192) {
        int m = i - 16384;
        int k = m >> 6, n = m & 63;
        T2l[n * 128 + k] = f2bf(W2l[m]);
        T2r[n * 128 + k] = f2bf(W2r[m]);
    }
}

// ---------------- MFMA dual GEMM ----------------
// A[M][128] row-major (fp32 if A_F32 else bf16); WTl/WTr[NC][128] bf16.
// Pl = A@Wl stored bf16, Qr = A@Wr stored f32. One wave = 16 output rows.
// mfma_f32_16x16x32_bf16 fragments: A lane l -> row l&15, k=(l>>4)*8+j;
// B lane l -> col l&15, same k; D: col=lane&15, row=(lane>>4)*4+reg.

template <int NC, bool A_F32>
__global__ __launch_bounds__(256) void mfma_dual_gemm(
    const void* __restrict__ Av,
    const unsigned short* __restrict__ WTl,
    const unsigned short* __restrict__ WTr,
    unsigned short* __restrict__ Pl,
    float* __restrict__ Qr, int M) {
    const int wave = threadIdx.x >> 6;
    const int lane = threadIdx.x & 63;
    const int m0 = blockIdx.x * 64 + wave * 16;
    const int lr = lane & 15;
    const int lk = lane >> 4;

    int arow = m0 + lr;
    if (arow >= M) arow = M - 1;

    bf16x8 af[4];
    if (A_F32) {
        const float* Ab = (const float*)Av + (size_t)arow * 128 + lk * 8;
#pragma unroll
        for (int s = 0; s < 4; ++s) {
            float4 v0 = *(const float4*)(Ab + s * 32);
            float4 v1 = *(const float4*)(Ab + s * 32 + 4);
            unsigned short t[8] = {f2bf(v0.x), f2bf(v0.y), f2bf(v0.z), f2bf(v0.w),
                                   f2bf(v1.x), f2bf(v1.y), f2bf(v1.z), f2bf(v1.w)};
            af[s] = *(const bf16x8*)t;
        }
    } else {
        const unsigned short* Ab = (const unsigned short*)Av + (size_t)arow * 128 + lk * 8;
#pragma unroll
        for (int s = 0; s < 4; ++s) af[s] = *(const bf16x8*)(Ab + s * 32);
    }

#pragma unroll
    for (int ct = 0; ct < NC / 16; ++ct) {
        const unsigned short* Bl = WTl + (size_t)(ct * 16 + lr) * 128 + lk * 8;
        const unsigned short* Br = WTr + (size_t)(ct * 16 + lr) * 128 + lk * 8;
        f32x4 accL = {0.f, 0.f, 0.f, 0.f};
        f32x4 accR = {0.f, 0.f, 0.f, 0.f};
#pragma unroll
        for (int s = 0; s < 4; ++s) {
            bf16x8 bl = *(const bf16x8*)(Bl + s * 32);
            bf16x8 br = *(const bf16x8*)(Br + s * 32);
            accL = __builtin_amdgcn_mfma_f32_16x16x32_bf16(af[s], bl, accL, 0, 0, 0);
            accR = __builtin_amdgcn_mfma_f32_16x16x32_bf16(af[s], br, accR, 0, 0, 0);
        }
#pragma unroll
        for (int r = 0; r < 4; ++r) {
            int gr = m0 + lk * 4 + r;
            if (gr < M) {
                Pl[(size_t)gr * NC + ct * 16 + lr] = f2bf(accL[r]);
                Qr[(size_t)gr * NC + ct * 16 + lr] = accR[r];
            }
        }
    }
}

// ---------------- aggregation ----------------
// layer 1: h[n] = relu( mean(p[src]) + q[n] + b1 ); p,h bf16; q f32; 128 ch.
// 4-deep unroll: 4 independent row gathers in flight per lane.
__global__ __launch_bounds__(256) void agg1_kernel(const unsigned short* __restrict__ p,
                                                   const float* __restrict__ q,
                                                   const float* __restrict__ b1,
                                                   const int* __restrict__ row_start,
                                                   const int* __restrict__ csr_src,
                                                   unsigned short* __restrict__ h, int N) {
    int wave = threadIdx.x >> 6;
    int lane = threadIdx.x & 63;
    int n = blockIdx.x * 4 + wave;
    if (n >= N) return;
    int s0 = row_start[n], s1 = row_start[n + 1];
    float ax = 0.f, ay = 0.f, bx = 0.f, by = 0.f;
    float cx = 0.f, cy = 0.f, dx = 0.f, dy = 0.f;
    int e = s0;
    for (; e + 3 < s1; e += 4) {
        int i0 = csr_src[e],     i1 = csr_src[e + 1];
        int i2 = csr_src[e + 2], i3 = csr_src[e + 3];
        unsigned u0 = *(const unsigned*)(p + (size_t)i0 * 128 + lane * 2);
        unsigned u1 = *(const unsigned*)(p + (size_t)i1 * 128 + lane * 2);
        unsigned u2 = *(const unsigned*)(p + (size_t)i2 * 128 + lane * 2);
        unsigned u3 = *(const unsigned*)(p + (size_t)i3 * 128 + lane * 2);
        ax += bf_lo(u0); ay += bf_hi(u0);
        bx += bf_lo(u1); by += bf_hi(u1);
        cx += bf_lo(u2); cy += bf_hi(u2);
        dx += bf_lo(u3); dy += bf_hi(u3);
    }
    for (; e < s1; ++e) {
        unsigned u0 = *(const unsigned*)(p + (size_t)csr_src[e] * 128 + lane * 2);
        ax += bf_lo(u0); ay += bf_hi(u0);
    }
    float sx = (ax + bx) + (cx + dx), sy = (ay + by) + (cy + dy);
    float inv = 1.0f / (float)max(s1 - s0, 1);
    float2 qq = *(const float2*)(q + (size_t)n * 128 + lane * 2);
    float2 bb = *(const float2*)(b1 + lane * 2);
    float hx = fmaxf(fmaf(sx, inv, qq.x + bb.x), 0.0f);
    float hy = fmaxf(fmaf(sy, inv, qq.y + bb.y), 0.0f);
    ushort2 o; o.x = f2bf(hx); o.y = f2bf(hy);
    *(ushort2*)(h + (size_t)n * 128 + lane * 2) = o;
}

// layer 2: out[n] = mean(g[src]) + r[n] + b2; g bf16; r,out f32; 64 ch.
__global__ __launch_bounds__(256) void agg2_kernel(const unsigned short* __restrict__ g,
                                                   const float* __restrict__ r,
                                                   const float* __restrict__ b2,
                                                   const int* __restrict__ row_start,
                                                   const int* __restrict__ csr_src,
                                                   float* __restrict__ out, int N) {
    int wave = threadIdx.x >> 6;
    int lane = threadIdx.x & 63;
    int n = blockIdx.x * 4 + wave;
    if (n >= N) return;
    int s0 = row_start[n], s1 = row_start[n + 1];
    float a0 = 0.f, a1 = 0.f, a2 = 0.f, a3 = 0.f;
    int e = s0;
    for (; e + 3 < s1; e += 4) {
        int i0 = csr_src[e],     i1 = csr_src[e + 1];
        int i2 = csr_src[e + 2], i3 = csr_src[e + 3];
        unsigned v0 = (unsigned)g[(size_t)i0 * 64 + lane] << 16;
        unsigned v1 = (unsigned)g[(size_t)i1 * 64 + lane] << 16;
        unsigned v2 = (unsigned)g[(size_t)i2 * 64 + lane] << 16;
        unsigned v3 = (unsigned)g[(size_t)i3 * 64 + lane] << 16;
        a0 += __builtin_bit_cast(float, v0);
        a1 += __builtin_bit_cast(float, v1);
        a2 += __builtin_bit_cast(float, v2);
        a3 += __builtin_bit_cast(float, v3);
    }
    for (; e < s1; ++e) {
        unsigned v0 = (unsigned)g[(size_t)csr_src[e] * 64 + lane] << 16;
        a0 += __builtin_bit_cast(float, v0);
    }
    float inv = 1.0f / (float)max(s1 - s0, 1);
    out[(size_t)n * 64 + lane] = fmaf((a0 + a1) + (a2 + a3), inv,
                                      r[(size_t)n * 64 + lane] + b2[lane]);
}

// ---------------------------------------------------------------------------

extern "C" void kernel_launch(void* const* d_in, const int* in_sizes, int n_in,
                              void* d_out, int out_size, void* d_ws, size_t ws_size,
                              hipStream_t stream) {
    const float* x    = (const float*)d_in[0];
    const int*   ei   = (const int*)d_in[1];
    const float* W1_l = (const float*)d_in[2];
    const float* b1   = (const float*)d_in[3];
    const float* W1_r = (const float*)d_in[4];
    const float* W2_l = (const float*)d_in[5];
    const float* b2   = (const float*)d_in[6];
    const float* W2_r = (const float*)d_in[7];

    const int N = in_sizes[0] / 128;   // 50000
    const int E = in_sizes[1] / 2;     // 800000
    const int* e_src = ei;
    const int* e_dst = ei + E;

    // ---- workspace layout ----
    char* ws = (char*)d_ws;
    auto align256 = [](size_t v) { return (v + 255) & ~(size_t)255; };
    size_t off = 0;
    int* row_start = (int*)(ws + off); off += align256((size_t)(N + 1) * 4);
    int* cnt       = (int*)(ws + off); off += align256((size_t)N * 4);   // cnt+cursor adjacent:
    int* cursor    = (int*)(ws + off); off += align256((size_t)N * 4);   // single memset below
    int* bsum      = (int*)(ws + off); off += align256(1024);
    int* csr_src   = (int*)(ws + off); off += align256((size_t)E * 4);
    unsigned short* h_bf  = (unsigned short*)(ws + off); off += align256((size_t)N * 128 * 2);
    unsigned short* pg_bf = (unsigned short*)(ws + off); off += align256((size_t)N * 128 * 2);
    float* qr_f32         = (float*)(ws + off);          off += align256((size_t)N * 128 * 4);
    unsigned short* wt1l  = (unsigned short*)(ws + off); off += align256(128 * 128 * 2);
    unsigned short* wt1r  = (unsigned short*)(ws + off); off += align256(128 * 128 * 2);
    unsigned short* wt2l  = (unsigned short*)(ws + off); off += align256(128 * 64 * 2);
    unsigned short* wt2r  = (unsigned short*)(ws + off); off += align256(128 * 64 * 2);
    float* out = (float*)d_out;

    const int nCsrWg = ((E + CSR_CHUNK - 1) / CSR_CHUNK) * 8;

    // ---- CSR build + weight prep ----
    hipMemsetAsync(cnt, 0, align256((size_t)N * 4) + (size_t)N * 4, stream); // cnt & cursor
    wt_all_kernel<<<(16384 + 8192 * 2 + 255) / 256 + 64, 256, 0, stream>>>(
        W1_l, W1_r, W2_l, W2_r, wt1l, wt1r, wt2l, wt2r);
    count_sliced_kernel<<<nCsrWg, 256, 0, stream>>>(e_dst, cnt, E, N);
    const int nb = (N + 255) / 256;
    scan_blocks_kernel<<<nb, 256, 0, stream>>>(cnt, row_start, bsum, N);
    scan_bsum_kernel<<<1, 256, 0, stream>>>(bsum, row_start, nb, N);
    add_off_kernel<<<nb, 256, 0, stream>>>(row_start, bsum, N);
    scatter_sliced_kernel<<<nCsrWg, 256, 0, stream>>>(e_src, e_dst, row_start,
                                                      cursor, csr_src, E, N);

    // ---- layer 1: p = x@W1_l (bf16), q = x@W1_r (f32); fp32 A fused cvt ----
    mfma_dual_gemm<128, true><<<(N + 63) / 64, 256, 0, stream>>>(
        x, wt1l, wt1r, pg_bf, qr_f32, N);
    agg1_kernel<<<(N + 3) / 4, 256, 0, stream>>>(pg_bf, qr_f32, b1, row_start,
                                                 csr_src, h_bf, N);

    // ---- layer 2: g = h@W2_l (bf16), r = h@W2_r (f32) ----
    mfma_dual_gemm<64, false><<<(N + 63) / 64, 256, 0, stream>>>(
        h_bf, wt2l, wt2r, pg_bf, qr_f32, N);
    agg2_kernel<<<(N + 3) / 4, 256, 0, stream>>>(pg_bf, qr_f32, b2, row_start,
                                                 csr_src, out, N);
}

// Round 5
// 211.935 us; speedup vs baseline: 1.7186x; 1.0685x over previous
//
#include <hip/hip_runtime.h>
#include <hip/hip_bf16.h>

// ---------------------------------------------------------------------------
// GraphSAGE 2-layer forward.
//   h   = relu( mean_agg(x) @ W1_l + b1 + x @ W1_r )
//   out =       mean_agg(h) @ W2_l + b2 + h @ W2_r
// agg(x)@W == agg(x@W): transform-then-aggregate.
// bf16 MFMA GEMMs; bf16 gather buffers (p,g) AND addends (q,r); fp32 out.
// CSR build, XCD-sliced (blockIdx&7 == node-slice == XCD under round-robin
// dispatch): count stores per-edge rank (atomic return value), scatter is
// then atomic-free. Slices partition nodes -> exactly-once, placement-safe.
// ---------------------------------------------------------------------------

typedef __attribute__((ext_vector_type(8))) short bf16x8;
typedef __attribute__((ext_vector_type(4))) float f32x4;

static __device__ __forceinline__ float bf_lo(unsigned u) {
    u <<= 16; return __builtin_bit_cast(float, u);
}
static __device__ __forceinline__ float bf_hi(unsigned u) {
    u &= 0xffff0000u; return __builtin_bit_cast(float, u);
}
static __device__ __forceinline__ float bf1(unsigned short s) {
    unsigned u = (unsigned)s << 16; return __builtin_bit_cast(float, u);
}
static __device__ __forceinline__ unsigned short f2bf(float f) {
    __hip_bfloat16 b = __float2bfloat16(f);
    return __builtin_bit_cast(unsigned short, b);
}

#define CSR_CHUNK 8192

// ---------------- weight prep + cnt zero (one launch) ----------------
// W[K][N] f32 -> WT[N][K] bf16 for W1_l/W1_r (128x128), W2_l/W2_r (128x64).
// Also zeroes cnt[N] (grid-stride) so no separate memset dispatch is needed.

__global__ __launch_bounds__(256) void wt_all_kernel(const float* __restrict__ W1l,
                                                     const float* __restrict__ W1r,
                                                     const float* __restrict__ W2l,
                                                     const float* __restrict__ W2r,
                                                     unsigned short* __restrict__ T1l,
                                                     unsigned short* __restrict__ T1r,
                                                     unsigned short* __restrict__ T2l,
                                                     unsigned short* __restrict__ T2r,
                                                     int* __restrict__ cnt, int N) {
    int i = blockIdx.x * 256 + threadIdx.x;
    int nthreads = gridDim.x * 256;
    for (int z = i; z < N; z += nthreads) cnt[z] = 0;
    if (i < 16384) {
        int k = i >> 7, n = i & 127;
        T1l[n * 128 + k] = f2bf(W1l[i]);
        T1r[n * 128 + k] = f2bf(W1r[i]);
    } else if (i < 16384 + 8192) {
        int m = i - 16384;
        int k = m >> 6, n = m & 63;
        T2l[n * 128 + k] = f2bf(W2l[m]);
        T2r[n * 128 + k] = f2bf(W2r[m]);
    }
}

// ---------------- CSR build (XCD-sliced, rank-based) ----------------

__global__ __launch_bounds__(256) void count_rank_kernel(const int* __restrict__ dst,
                                                         int* __restrict__ cnt,
                                                         unsigned short* __restrict__ rank,
                                                         int E, int N) {
    const int j = blockIdx.x & 7;
    const int chunk = blockIdx.x >> 3;
    const int sliceW = (N + 7) >> 3;
    const int lo = j * sliceW;
    const int hi = min(N, lo + sliceW);
    const int base = chunk * CSR_CHUNK;
    const int end = min(E, base + CSR_CHUNK);
    for (int e = base + threadIdx.x; e < end; e += 256) {
        int d = dst[e];
        if (d >= lo && d < hi) {
            int r = atomicAdd(&cnt[d], 1);
            rank[e] = (unsigned short)r;
        }
    }
}

__global__ __launch_bounds__(256) void scan_blocks_kernel(const int* __restrict__ cnt,
                                                          int* __restrict__ row_start,
                                                          int* __restrict__ bsum, int N) {
    __shared__ int lds[256];
    int i = blockIdx.x * 256 + threadIdx.x;
    int v = (i < N) ? cnt[i] : 0;
    lds[threadIdx.x] = v;
    __syncthreads();
    for (int off = 1; off < 256; off <<= 1) {
        int t = (threadIdx.x >= off) ? lds[threadIdx.x - off] : 0;
        __syncthreads();
        lds[threadIdx.x] += t;
        __syncthreads();
    }
    if (i < N) row_start[i] = lds[threadIdx.x] - v;
    if (threadIdx.x == 255) bsum[blockIdx.x] = lds[255];
}

// block b: prefix = sum(bsum[0..b)) via LDS reduce; row_start[i] += prefix.
// Also writes row_start[N] = E (total edge count is known a priori).
__global__ __launch_bounds__(256) void add_off_kernel(int* __restrict__ row_start,
                                                      const int* __restrict__ bsum,
                                                      int N, int E) {
    __shared__ int lds[256];
    int b = blockIdx.x;
    lds[threadIdx.x] = (threadIdx.x < b) ? bsum[threadIdx.x] : 0;
    __syncthreads();
    for (int off = 128; off > 0; off >>= 1) {
        if (threadIdx.x < off) lds[threadIdx.x] += lds[threadIdx.x + off];
        __syncthreads();
    }
    int prefix = lds[0];
    int i = b * 256 + threadIdx.x;
    if (i < N) row_start[i] += prefix;
    if (b == 0 && threadIdx.x == 0) row_start[N] = E;
}

__global__ __launch_bounds__(256) void scatter_kernel(const int* __restrict__ src,
                                                      const int* __restrict__ dst,
                                                      const unsigned short* __restrict__ rank,
                                                      const int* __restrict__ row_start,
                                                      int* __restrict__ csr_src,
                                                      int E, int N) {
    const int j = blockIdx.x & 7;
    const int chunk = blockIdx.x >> 3;
    const int sliceW = (N + 7) >> 3;
    const int lo = j * sliceW;
    const int hi = min(N, lo + sliceW);
    const int base = chunk * CSR_CHUNK;
    const int end = min(E, base + CSR_CHUNK);
    for (int e = base + threadIdx.x; e < end; e += 256) {
        int d = dst[e];
        if (d >= lo && d < hi) {
            csr_src[row_start[d] + (int)rank[e]] = src[e];
        }
    }
}

// ---------------- MFMA dual GEMM ----------------
// A[M][128] row-major (fp32 if A_F32 else bf16); WTl/WTr[NC][128] bf16 (=W^T).
// Pl = A@Wl (bf16), Qr = A@Wr (bf16). One wave = 16 output rows.
// mfma_f32_16x16x32_bf16: A lane l -> row l&15, k=(l>>4)*8+j; B lane l ->
// col l&15, same k; D: col=lane&15, row=(lane>>4)*4+reg.

template <int NC, bool A_F32>
__global__ __launch_bounds__(256) void mfma_dual_gemm(
    const void* __restrict__ Av,
    const unsigned short* __restrict__ WTl,
    const unsigned short* __restrict__ WTr,
    unsigned short* __restrict__ Pl,
    unsigned short* __restrict__ Qr, int M) {
    const int wave = threadIdx.x >> 6;
    const int lane = threadIdx.x & 63;
    const int m0 = blockIdx.x * 64 + wave * 16;
    const int lr = lane & 15;
    const int lk = lane >> 4;

    int arow = m0 + lr;
    if (arow >= M) arow = M - 1;

    bf16x8 af[4];
    if (A_F32) {
        const float* Ab = (const float*)Av + (size_t)arow * 128 + lk * 8;
#pragma unroll
        for (int s = 0; s < 4; ++s) {
            float4 v0 = *(const float4*)(Ab + s * 32);
            float4 v1 = *(const float4*)(Ab + s * 32 + 4);
            unsigned short t[8] = {f2bf(v0.x), f2bf(v0.y), f2bf(v0.z), f2bf(v0.w),
                                   f2bf(v1.x), f2bf(v1.y), f2bf(v1.z), f2bf(v1.w)};
            af[s] = *(const bf16x8*)t;
        }
    } else {
        const unsigned short* Ab = (const unsigned short*)Av + (size_t)arow * 128 + lk * 8;
#pragma unroll
        for (int s = 0; s < 4; ++s) af[s] = *(const bf16x8*)(Ab + s * 32);
    }

#pragma unroll
    for (int ct = 0; ct < NC / 16; ++ct) {
        const unsigned short* Bl = WTl + (size_t)(ct * 16 + lr) * 128 + lk * 8;
        const unsigned short* Br = WTr + (size_t)(ct * 16 + lr) * 128 + lk * 8;
        f32x4 accL = {0.f, 0.f, 0.f, 0.f};
        f32x4 accR = {0.f, 0.f, 0.f, 0.f};
#pragma unroll
        for (int s = 0; s < 4; ++s) {
            bf16x8 bl = *(const bf16x8*)(Bl + s * 32);
            bf16x8 br = *(const bf16x8*)(Br + s * 32);
            accL = __builtin_amdgcn_mfma_f32_16x16x32_bf16(af[s], bl, accL, 0, 0, 0);
            accR = __builtin_amdgcn_mfma_f32_16x16x32_bf16(af[s], br, accR, 0, 0, 0);
        }
#pragma unroll
        for (int r = 0; r < 4; ++r) {
            int gr = m0 + lk * 4 + r;
            if (gr < M) {
                Pl[(size_t)gr * NC + ct * 16 + lr] = f2bf(accL[r]);
                Qr[(size_t)gr * NC + ct * 16 + lr] = f2bf(accR[r]);
            }
        }
    }
}

// ---------------- aggregation ----------------
// layer 1: h[n] = relu( mean(p[src]) + q[n] + b1 ); p,q,h bf16; 128 ch.
// 8-deep unroll: 8 independent row gathers in flight per lane.
__global__ __launch_bounds__(256) void agg1_kernel(const unsigned short* __restrict__ p,
                                                   const unsigned short* __restrict__ q,
                                                   const float* __restrict__ b1,
                                                   const int* __restrict__ row_start,
                                                   const int* __restrict__ csr_src,
                                                   unsigned short* __restrict__ h, int N) {
    int wave = threadIdx.x >> 6;
    int lane = threadIdx.x & 63;
    int n = blockIdx.x * 4 + wave;
    if (n >= N) return;
    int s0 = row_start[n], s1 = row_start[n + 1];
    float sx = 0.f, sy = 0.f;
    int e = s0;
    for (; e + 7 < s1; e += 8) {
        unsigned u0 = *(const unsigned*)(p + (size_t)csr_src[e]     * 128 + lane * 2);
        unsigned u1 = *(const unsigned*)(p + (size_t)csr_src[e + 1] * 128 + lane * 2);
        unsigned u2 = *(const unsigned*)(p + (size_t)csr_src[e + 2] * 128 + lane * 2);
        unsigned u3 = *(const unsigned*)(p + (size_t)csr_src[e + 3] * 128 + lane * 2);
        unsigned u4 = *(const unsigned*)(p + (size_t)csr_src[e + 4] * 128 + lane * 2);
        unsigned u5 = *(const unsigned*)(p + (size_t)csr_src[e + 5] * 128 + lane * 2);
        unsigned u6 = *(const unsigned*)(p + (size_t)csr_src[e + 6] * 128 + lane * 2);
        unsigned u7 = *(const unsigned*)(p + (size_t)csr_src[e + 7] * 128 + lane * 2);
        float ax = (bf_lo(u0) + bf_lo(u1)) + (bf_lo(u2) + bf_lo(u3));
        float bx = (bf_lo(u4) + bf_lo(u5)) + (bf_lo(u6) + bf_lo(u7));
        float ay = (bf_hi(u0) + bf_hi(u1)) + (bf_hi(u2) + bf_hi(u3));
        float by = (bf_hi(u4) + bf_hi(u5)) + (bf_hi(u6) + bf_hi(u7));
        sx += ax + bx; sy += ay + by;
    }
    for (; e < s1; ++e) {
        unsigned u0 = *(const unsigned*)(p + (size_t)csr_src[e] * 128 + lane * 2);
        sx += bf_lo(u0); sy += bf_hi(u0);
    }
    float inv = 1.0f / (float)max(s1 - s0, 1);
    unsigned qq = *(const unsigned*)(q + (size_t)n * 128 + lane * 2);
    float2 bb = *(const float2*)(b1 + lane * 2);
    float hx = fmaxf(fmaf(sx, inv, bf_lo(qq) + bb.x), 0.0f);
    float hy = fmaxf(fmaf(sy, inv, bf_hi(qq) + bb.y), 0.0f);
    ushort2 o; o.x = f2bf(hx); o.y = f2bf(hy);
    *(ushort2*)(h + (size_t)n * 128 + lane * 2) = o;
}

// layer 2: out[n] = mean(g[src]) + r[n] + b2; g,r bf16; out f32; 64 ch.
__global__ __launch_bounds__(256) void agg2_kernel(const unsigned short* __restrict__ g,
                                                   const unsigned short* __restrict__ r,
                                                   const float* __restrict__ b2,
                                                   const int* __restrict__ row_start,
                                                   const int* __restrict__ csr_src,
                                                   float* __restrict__ out, int N) {
    int wave = threadIdx.x >> 6;
    int lane = threadIdx.x & 63;
    int n = blockIdx.x * 4 + wave;
    if (n >= N) return;
    int s0 = row_start[n], s1 = row_start[n + 1];
    float s = 0.f;
    int e = s0;
    for (; e + 7 < s1; e += 8) {
        float v0 = bf1(g[(size_t)csr_src[e]     * 64 + lane]);
        float v1 = bf1(g[(size_t)csr_src[e + 1] * 64 + lane]);
        float v2 = bf1(g[(size_t)csr_src[e + 2] * 64 + lane]);
        float v3 = bf1(g[(size_t)csr_src[e + 3] * 64 + lane]);
        float v4 = bf1(g[(size_t)csr_src[e + 4] * 64 + lane]);
        float v5 = bf1(g[(size_t)csr_src[e + 5] * 64 + lane]);
        float v6 = bf1(g[(size_t)csr_src[e + 6] * 64 + lane]);
        float v7 = bf1(g[(size_t)csr_src[e + 7] * 64 + lane]);
        s += ((v0 + v1) + (v2 + v3)) + ((v4 + v5) + (v6 + v7));
    }
    for (; e < s1; ++e) s += bf1(g[(size_t)csr_src[e] * 64 + lane]);
    float inv = 1.0f / (float)max(s1 - s0, 1);
    out[(size_t)n * 64 + lane] = fmaf(s, inv, bf1(r[(size_t)n * 64 + lane]) + b2[lane]);
}

// ---------------------------------------------------------------------------

extern "C" void kernel_launch(void* const* d_in, const int* in_sizes, int n_in,
                              void* d_out, int out_size, void* d_ws, size_t ws_size,
                              hipStream_t stream) {
    const float* x    = (const float*)d_in[0];
    const int*   ei   = (const int*)d_in[1];
    const float* W1_l = (const float*)d_in[2];
    const float* b1   = (const float*)d_in[3];
    const float* W1_r = (const float*)d_in[4];
    const float* W2_l = (const float*)d_in[5];
    const float* b2   = (const float*)d_in[6];
    const float* W2_r = (const float*)d_in[7];

    const int N = in_sizes[0] / 128;   // 50000
    const int E = in_sizes[1] / 2;     // 800000
    const int* e_src = ei;
    const int* e_dst = ei + E;

    // ---- workspace layout ----
    char* ws = (char*)d_ws;
    auto align256 = [](size_t v) { return (v + 255) & ~(size_t)255; };
    size_t off = 0;
    int* row_start = (int*)(ws + off); off += align256((size_t)(N + 1) * 4);
    int* cnt       = (int*)(ws + off); off += align256((size_t)N * 4);
    int* bsum      = (int*)(ws + off); off += align256(1024);
    unsigned short* rank = (unsigned short*)(ws + off); off += align256((size_t)E * 2);
    int* csr_src   = (int*)(ws + off); off += align256((size_t)E * 4);
    unsigned short* h_bf  = (unsigned short*)(ws + off); off += align256((size_t)N * 128 * 2);
    unsigned short* pg_bf = (unsigned short*)(ws + off); off += align256((size_t)N * 128 * 2);
    unsigned short* qr_bf = (unsigned short*)(ws + off); off += align256((size_t)N * 128 * 2);
    unsigned short* wt1l  = (unsigned short*)(ws + off); off += align256(128 * 128 * 2);
    unsigned short* wt1r  = (unsigned short*)(ws + off); off += align256(128 * 128 * 2);
    unsigned short* wt2l  = (unsigned short*)(ws + off); off += align256(128 * 64 * 2);
    unsigned short* wt2r  = (unsigned short*)(ws + off); off += align256(128 * 64 * 2);
    float* out = (float*)d_out;

    const int nCsrWg = ((E + CSR_CHUNK - 1) / CSR_CHUNK) * 8;
    const int nb = (N + 255) / 256;

    // ---- weight prep + cnt zero, then CSR build ----
    wt_all_kernel<<<128, 256, 0, stream>>>(W1_l, W1_r, W2_l, W2_r,
                                           wt1l, wt1r, wt2l, wt2r, cnt, N);
    count_rank_kernel<<<nCsrWg, 256, 0, stream>>>(e_dst, cnt, rank, E, N);
    scan_blocks_kernel<<<nb, 256, 0, stream>>>(cnt, row_start, bsum, N);
    add_off_kernel<<<nb, 256, 0, stream>>>(row_start, bsum, N, E);
    scatter_kernel<<<nCsrWg, 256, 0, stream>>>(e_src, e_dst, rank, row_start,
                                               csr_src, E, N);

    // ---- layer 1: p = x@W1_l, q = x@W1_r (both bf16); fused f32->bf16 A ----
    mfma_dual_gemm<128, true><<<(N + 63) / 64, 256, 0, stream>>>(
        x, wt1l, wt1r, pg_bf, qr_bf, N);
    agg1_kernel<<<(N + 3) / 4, 256, 0, stream>>>(pg_bf, qr_bf, b1, row_start,
                                                 csr_src, h_bf, N);

    // ---- layer 2: g = h@W2_l, r = h@W2_r (both bf16) ----
    mfma_dual_gemm<64, false><<<(N + 63) / 64, 256, 0, stream>>>(
        h_bf, wt2l, wt2r, pg_bf, qr_bf, N);
    agg2_kernel<<<(N + 3) / 4, 256, 0, stream>>>(pg_bf, qr_bf, b2, row_start,
                                                 csr_src, out, N);
}

// Round 6
// 202.221 us; speedup vs baseline: 1.8012x; 1.0480x over previous
//
#include <hip/hip_runtime.h>
#include <hip/hip_bf16.h>

// ---------------------------------------------------------------------------
// GraphSAGE 2-layer forward.
//   h   = relu( mean_agg(x) @ W1_l + b1 + x @ W1_r )
//   out =       mean_agg(h) @ W2_l + b2 + h @ W2_r
// agg(x)@W == agg(x@W): transform-then-aggregate.
// bf16 MFMA GEMMs; bf16 gather buffers (p,g) and addends (q,r); fp32 out.
// CSR build:
//   count: UNSLICED, contiguous-chunk -> rank[e] lines have a single writer
//          (full-line writes, no cross-XCD ping-pong); atomic returns rank.
//   scatter: dst-sliced (blockIdx&7 = node slice = XCD under round-robin) ->
//          csr_src writes are slice-contiguous and single-XCD. Atomic-free.
// ---------------------------------------------------------------------------

typedef __attribute__((ext_vector_type(8))) short bf16x8;
typedef __attribute__((ext_vector_type(4))) float f32x4;

static __device__ __forceinline__ float bf_lo(unsigned u) {
    u <<= 16; return __builtin_bit_cast(float, u);
}
static __device__ __forceinline__ float bf_hi(unsigned u) {
    u &= 0xffff0000u; return __builtin_bit_cast(float, u);
}
static __device__ __forceinline__ float bf1(unsigned short s) {
    unsigned u = (unsigned)s << 16; return __builtin_bit_cast(float, u);
}
static __device__ __forceinline__ unsigned short f2bf(float f) {
    __hip_bfloat16 b = __float2bfloat16(f);
    return __builtin_bit_cast(unsigned short, b);
}

#define SCAT_CHUNK 4096

// ---------------- weight prep + cnt zero (one launch) ----------------

__global__ __launch_bounds__(256) void wt_all_kernel(const float* __restrict__ W1l,
                                                     const float* __restrict__ W1r,
                                                     const float* __restrict__ W2l,
                                                     const float* __restrict__ W2r,
                                                     unsigned short* __restrict__ T1l,
                                                     unsigned short* __restrict__ T1r,
                                                     unsigned short* __restrict__ T2l,
                                                     unsigned short* __restrict__ T2r,
                                                     int* __restrict__ cnt, int N) {
    int i = blockIdx.x * 256 + threadIdx.x;
    int nthreads = gridDim.x * 256;
    for (int z = i; z < N; z += nthreads) cnt[z] = 0;
    if (i < 16384) {
        int k = i >> 7, n = i & 127;
        T1l[n * 128 + k] = f2bf(W1l[i]);
        T1r[n * 128 + k] = f2bf(W1r[i]);
    } else if (i < 16384 + 8192) {
        int m = i - 16384;
        int k = m >> 6, n = m & 63;
        T2l[n * 128 + k] = f2bf(W2l[m]);
        T2r[n * 128 + k] = f2bf(W2r[m]);
    }
}

// ---------------- CSR build ----------------
// count: each thread owns 4 consecutive edges (E is a multiple of 4).
// rank store is one aligned ushort4 -> single writer per cache line.

__global__ __launch_bounds__(256) void count_rank_kernel(const int* __restrict__ dst,
                                                         int* __restrict__ cnt,
                                                         unsigned short* __restrict__ rank,
                                                         int E) {
    int base = (blockIdx.x * 256 + threadIdx.x) * 4;
    if (base >= E) return;
    int4 d4 = *(const int4*)(dst + base);
    ushort4 r;
    r.x = (unsigned short)atomicAdd(&cnt[d4.x], 1);
    r.y = (unsigned short)atomicAdd(&cnt[d4.y], 1);
    r.z = (unsigned short)atomicAdd(&cnt[d4.z], 1);
    r.w = (unsigned short)atomicAdd(&cnt[d4.w], 1);
    *(ushort4*)(rank + base) = r;
}

__global__ __launch_bounds__(256) void scan_blocks_kernel(const int* __restrict__ cnt,
                                                          int* __restrict__ row_start,
                                                          int* __restrict__ bsum, int N) {
    __shared__ int lds[256];
    int i = blockIdx.x * 256 + threadIdx.x;
    int v = (i < N) ? cnt[i] : 0;
    lds[threadIdx.x] = v;
    __syncthreads();
    for (int off = 1; off < 256; off <<= 1) {
        int t = (threadIdx.x >= off) ? lds[threadIdx.x - off] : 0;
        __syncthreads();
        lds[threadIdx.x] += t;
        __syncthreads();
    }
    if (i < N) row_start[i] = lds[threadIdx.x] - v;
    if (threadIdx.x == 255) bsum[blockIdx.x] = lds[255];
}

// block b: prefix = sum(bsum[0..b)); row_start[i] += prefix; row_start[N]=E.
__global__ __launch_bounds__(256) void add_off_kernel(int* __restrict__ row_start,
                                                      const int* __restrict__ bsum,
                                                      int N, int E) {
    __shared__ int lds[256];
    int b = blockIdx.x;
    lds[threadIdx.x] = (threadIdx.x < b) ? bsum[threadIdx.x] : 0;
    __syncthreads();
    for (int off = 128; off > 0; off >>= 1) {
        if (threadIdx.x < off) lds[threadIdx.x] += lds[threadIdx.x + off];
        __syncthreads();
    }
    int prefix = lds[0];
    int i = b * 256 + threadIdx.x;
    if (i < N) row_start[i] += prefix;
    if (b == 0 && threadIdx.x == 0) row_start[N] = E;
}

// scatter: dst-sliced, atomic-free, vectorized 4-edge body.
__global__ __launch_bounds__(256) void scatter_kernel(const int* __restrict__ src,
                                                      const int* __restrict__ dst,
                                                      const unsigned short* __restrict__ rank,
                                                      const int* __restrict__ row_start,
                                                      int* __restrict__ csr_src,
                                                      int E, int N) {
    const int j = blockIdx.x & 7;
    const int chunk = blockIdx.x >> 3;
    const int sliceW = (N + 7) >> 3;
    const int lo = j * sliceW;
    const int hi = min(N, lo + sliceW);
    const int base = chunk * SCAT_CHUNK;
    const int end = min(E, base + SCAT_CHUNK);
    for (int e = base + threadIdx.x * 4; e < end; e += 1024) {
        int4 d4 = *(const int4*)(dst + e);
        ushort4 r4 = *(const ushort4*)(rank + e);
        int4 s4 = *(const int4*)(src + e);
        if (d4.x >= lo && d4.x < hi) csr_src[row_start[d4.x] + (int)r4.x] = s4.x;
        if (d4.y >= lo && d4.y < hi) csr_src[row_start[d4.y] + (int)r4.y] = s4.y;
        if (d4.z >= lo && d4.z < hi) csr_src[row_start[d4.z] + (int)r4.z] = s4.z;
        if (d4.w >= lo && d4.w < hi) csr_src[row_start[d4.w] + (int)r4.w] = s4.w;
    }
}

// ---------------- MFMA dual GEMM ----------------
// A[M][128] row-major (fp32 if A_F32 else bf16); WTl/WTr[NC][128] bf16 (=W^T).
// Pl = A@Wl (bf16), Qr = A@Wr (bf16). One wave = 16 output rows.
// mfma_f32_16x16x32_bf16: A lane l -> row l&15, k=(l>>4)*8+j; B lane l ->
// col l&15, same k; D: col=lane&15, row=(lane>>4)*4+reg.

template <int NC, bool A_F32>
__global__ __launch_bounds__(256) void mfma_dual_gemm(
    const void* __restrict__ Av,
    const unsigned short* __restrict__ WTl,
    const unsigned short* __restrict__ WTr,
    unsigned short* __restrict__ Pl,
    unsigned short* __restrict__ Qr, int M) {
    const int wave = threadIdx.x >> 6;
    const int lane = threadIdx.x & 63;
    const int m0 = blockIdx.x * 64 + wave * 16;
    const int lr = lane & 15;
    const int lk = lane >> 4;

    int arow = m0 + lr;
    if (arow >= M) arow = M - 1;

    bf16x8 af[4];
    if (A_F32) {
        const float* Ab = (const float*)Av + (size_t)arow * 128 + lk * 8;
#pragma unroll
        for (int s = 0; s < 4; ++s) {
            float4 v0 = *(const float4*)(Ab + s * 32);
            float4 v1 = *(const float4*)(Ab + s * 32 + 4);
            unsigned short t[8] = {f2bf(v0.x), f2bf(v0.y), f2bf(v0.z), f2bf(v0.w),
                                   f2bf(v1.x), f2bf(v1.y), f2bf(v1.z), f2bf(v1.w)};
            af[s] = *(const bf16x8*)t;
        }
    } else {
        const unsigned short* Ab = (const unsigned short*)Av + (size_t)arow * 128 + lk * 8;
#pragma unroll
        for (int s = 0; s < 4; ++s) af[s] = *(const bf16x8*)(Ab + s * 32);
    }

#pragma unroll
    for (int ct = 0; ct < NC / 16; ++ct) {
        const unsigned short* Bl = WTl + (size_t)(ct * 16 + lr) * 128 + lk * 8;
        const unsigned short* Br = WTr + (size_t)(ct * 16 + lr) * 128 + lk * 8;
        f32x4 accL = {0.f, 0.f, 0.f, 0.f};
        f32x4 accR = {0.f, 0.f, 0.f, 0.f};
#pragma unroll
        for (int s = 0; s < 4; ++s) {
            bf16x8 bl = *(const bf16x8*)(Bl + s * 32);
            bf16x8 br = *(const bf16x8*)(Br + s * 32);
            accL = __builtin_amdgcn_mfma_f32_16x16x32_bf16(af[s], bl, accL, 0, 0, 0);
            accR = __builtin_amdgcn_mfma_f32_16x16x32_bf16(af[s], br, accR, 0, 0, 0);
        }
#pragma unroll
        for (int r = 0; r < 4; ++r) {
            int gr = m0 + lk * 4 + r;
            if (gr < M) {
                Pl[(size_t)gr * NC + ct * 16 + lr] = f2bf(accL[r]);
                Qr[(size_t)gr * NC + ct * 16 + lr] = f2bf(accR[r]);
            }
        }
    }
}

// ---------------- aggregation ----------------
// layer 1: h[n] = relu( mean(p[src]) + q[n] + b1 ); p,q,h bf16; 128 ch.
__global__ __launch_bounds__(256) void agg1_kernel(const unsigned short* __restrict__ p,
                                                   const unsigned short* __restrict__ q,
                                                   const float* __restrict__ b1,
                                                   const int* __restrict__ row_start,
                                                   const int* __restrict__ csr_src,
                                                   unsigned short* __restrict__ h, int N) {
    int wave = threadIdx.x >> 6;
    int lane = threadIdx.x & 63;
    int n = blockIdx.x * 4 + wave;
    if (n >= N) return;
    int s0 = row_start[n], s1 = row_start[n + 1];
    float sx = 0.f, sy = 0.f;
    int e = s0;
    for (; e + 7 < s1; e += 8) {
        unsigned u0 = *(const unsigned*)(p + (size_t)csr_src[e]     * 128 + lane * 2);
        unsigned u1 = *(const unsigned*)(p + (size_t)csr_src[e + 1] * 128 + lane * 2);
        unsigned u2 = *(const unsigned*)(p + (size_t)csr_src[e + 2] * 128 + lane * 2);
        unsigned u3 = *(const unsigned*)(p + (size_t)csr_src[e + 3] * 128 + lane * 2);
        unsigned u4 = *(const unsigned*)(p + (size_t)csr_src[e + 4] * 128 + lane * 2);
        unsigned u5 = *(const unsigned*)(p + (size_t)csr_src[e + 5] * 128 + lane * 2);
        unsigned u6 = *(const unsigned*)(p + (size_t)csr_src[e + 6] * 128 + lane * 2);
        unsigned u7 = *(const unsigned*)(p + (size_t)csr_src[e + 7] * 128 + lane * 2);
        float ax = (bf_lo(u0) + bf_lo(u1)) + (bf_lo(u2) + bf_lo(u3));
        float bx = (bf_lo(u4) + bf_lo(u5)) + (bf_lo(u6) + bf_lo(u7));
        float ay = (bf_hi(u0) + bf_hi(u1)) + (bf_hi(u2) + bf_hi(u3));
        float by = (bf_hi(u4) + bf_hi(u5)) + (bf_hi(u6) + bf_hi(u7));
        sx += ax + bx; sy += ay + by;
    }
    for (; e < s1; ++e) {
        unsigned u0 = *(const unsigned*)(p + (size_t)csr_src[e] * 128 + lane * 2);
        sx += bf_lo(u0); sy += bf_hi(u0);
    }
    float inv = 1.0f / (float)max(s1 - s0, 1);
    unsigned qq = *(const unsigned*)(q + (size_t)n * 128 + lane * 2);
    float2 bb = *(const float2*)(b1 + lane * 2);
    float hx = fmaxf(fmaf(sx, inv, bf_lo(qq) + bb.x), 0.0f);
    float hy = fmaxf(fmaf(sy, inv, bf_hi(qq) + bb.y), 0.0f);
    ushort2 o; o.x = f2bf(hx); o.y = f2bf(hy);
    *(ushort2*)(h + (size_t)n * 128 + lane * 2) = o;
}

// layer 2: out[n] = mean(g[src]) + r[n] + b2; g,r bf16; out f32; 64 ch.
__global__ __launch_bounds__(256) void agg2_kernel(const unsigned short* __restrict__ g,
                                                   const unsigned short* __restrict__ r,
                                                   const float* __restrict__ b2,
                                                   const int* __restrict__ row_start,
                                                   const int* __restrict__ csr_src,
                                                   float* __restrict__ out, int N) {
    int wave = threadIdx.x >> 6;
    int lane = threadIdx.x & 63;
    int n = blockIdx.x * 4 + wave;
    if (n >= N) return;
    int s0 = row_start[n], s1 = row_start[n + 1];
    float s = 0.f;
    int e = s0;
    for (; e + 7 < s1; e += 8) {
        float v0 = bf1(g[(size_t)csr_src[e]     * 64 + lane]);
        float v1 = bf1(g[(size_t)csr_src[e + 1] * 64 + lane]);
        float v2 = bf1(g[(size_t)csr_src[e + 2] * 64 + lane]);
        float v3 = bf1(g[(size_t)csr_src[e + 3] * 64 + lane]);
        float v4 = bf1(g[(size_t)csr_src[e + 4] * 64 + lane]);
        float v5 = bf1(g[(size_t)csr_src[e + 5] * 64 + lane]);
        float v6 = bf1(g[(size_t)csr_src[e + 6] * 64 + lane]);
        float v7 = bf1(g[(size_t)csr_src[e + 7] * 64 + lane]);
        s += ((v0 + v1) + (v2 + v3)) + ((v4 + v5) + (v6 + v7));
    }
    for (; e < s1; ++e) s += bf1(g[(size_t)csr_src[e] * 64 + lane]);
    float inv = 1.0f / (float)max(s1 - s0, 1);
    out[(size_t)n * 64 + lane] = fmaf(s, inv, bf1(r[(size_t)n * 64 + lane]) + b2[lane]);
}

// ---------------------------------------------------------------------------

extern "C" void kernel_launch(void* const* d_in, const int* in_sizes, int n_in,
                              void* d_out, int out_size, void* d_ws, size_t ws_size,
                              hipStream_t stream) {
    const float* x    = (const float*)d_in[0];
    const int*   ei   = (const int*)d_in[1];
    const float* W1_l = (const float*)d_in[2];
    const float* b1   = (const float*)d_in[3];
    const float* W1_r = (const float*)d_in[4];
    const float* W2_l = (const float*)d_in[5];
    const float* b2   = (const float*)d_in[6];
    const float* W2_r = (const float*)d_in[7];

    const int N = in_sizes[0] / 128;   // 50000
    const int E = in_sizes[1] / 2;     // 800000
    const int* e_src = ei;
    const int* e_dst = ei + E;

    // ---- workspace layout ----
    char* ws = (char*)d_ws;
    auto align256 = [](size_t v) { return (v + 255) & ~(size_t)255; };
    size_t off = 0;
    int* row_start = (int*)(ws + off); off += align256((size_t)(N + 1) * 4);
    int* cnt       = (int*)(ws + off); off += align256((size_t)N * 4);
    int* bsum      = (int*)(ws + off); off += align256(1024);
    unsigned short* rank = (unsigned short*)(ws + off); off += align256((size_t)E * 2);
    int* csr_src   = (int*)(ws + off); off += align256((size_t)E * 4);
    unsigned short* h_bf  = (unsigned short*)(ws + off); off += align256((size_t)N * 128 * 2);
    unsigned short* pg_bf = (unsigned short*)(ws + off); off += align256((size_t)N * 128 * 2);
    unsigned short* qr_bf = (unsigned short*)(ws + off); off += align256((size_t)N * 128 * 2);
    unsigned short* wt1l  = (unsigned short*)(ws + off); off += align256(128 * 128 * 2);
    unsigned short* wt1r  = (unsigned short*)(ws + off); off += align256(128 * 128 * 2);
    unsigned short* wt2l  = (unsigned short*)(ws + off); off += align256(128 * 64 * 2);
    unsigned short* wt2r  = (unsigned short*)(ws + off); off += align256(128 * 64 * 2);
    float* out = (float*)d_out;

    const int nb = (N + 255) / 256;
    const int nCountWg = (E / 4 + 255) / 256;
    const int nScatWg = ((E + SCAT_CHUNK - 1) / SCAT_CHUNK) * 8;

    // ---- weight prep + cnt zero, then CSR build ----
    wt_all_kernel<<<128, 256, 0, stream>>>(W1_l, W1_r, W2_l, W2_r,
                                           wt1l, wt1r, wt2l, wt2r, cnt, N);
    count_rank_kernel<<<nCountWg, 256, 0, stream>>>(e_dst, cnt, rank, E);
    scan_blocks_kernel<<<nb, 256, 0, stream>>>(cnt, row_start, bsum, N);
    add_off_kernel<<<nb, 256, 0, stream>>>(row_start, bsum, N, E);
    scatter_kernel<<<nScatWg, 256, 0, stream>>>(e_src, e_dst, rank, row_start,
                                                csr_src, E, N);

    // ---- layer 1: p = x@W1_l, q = x@W1_r (both bf16); fused f32->bf16 A ----
    mfma_dual_gemm<128, true><<<(N + 63) / 64, 256, 0, stream>>>(
        x, wt1l, wt1r, pg_bf, qr_bf, N);
    agg1_kernel<<<(N + 3) / 4, 256, 0, stream>>>(pg_bf, qr_bf, b1, row_start,
                                                 csr_src, h_bf, N);

    // ---- layer 2: g = h@W2_l, r = h@W2_r (both bf16) ----
    mfma_dual_gemm<64, false><<<(N + 63) / 64, 256, 0, stream>>>(
        h_bf, wt2l, wt2r, pg_bf, qr_bf, N);
    agg2_kernel<<<(N + 3) / 4, 256, 0, stream>>>(pg_bf, qr_bf, b2, row_start,
                                                 csr_src, out, N);
}

// Round 7
// 164.269 us; speedup vs baseline: 2.2174x; 1.2310x over previous
//
#include <hip/hip_runtime.h>
#include <hip/hip_bf16.h>

// ---------------------------------------------------------------------------
// GraphSAGE 2-layer forward.
//   h   = relu( mean_agg(x) @ W1_l + b1 + x @ W1_r )
//   out =       mean_agg(h) @ W2_l + b2 + h @ W2_r
// agg(x)@W == agg(x@W): transform-then-aggregate.
// bf16 MFMA GEMMs; bf16 gather buffers (p,g) and addends (q,r); fp32 out.
// CSR build: count (unsliced, rank = atomic return, single-writer rank lines)
//            fused into the same dispatch as GEMM-1 (independent work);
//            scatter dst-sliced (blockIdx&7 = node slice) and atomic-free.
// Aggregation: 4 nodes per wave, 16 lanes/node, 16B(8ch)/lane -> each load
// instruction fetches 4 rows; 4-deep unroll = 16 rows in flight per wave.
// ---------------------------------------------------------------------------

typedef __attribute__((ext_vector_type(8))) short bf16x8;
typedef __attribute__((ext_vector_type(4))) float f32x4;

static __device__ __forceinline__ float bf_lo(unsigned u) {
    u <<= 16; return __builtin_bit_cast(float, u);
}
static __device__ __forceinline__ float bf_hi(unsigned u) {
    u &= 0xffff0000u; return __builtin_bit_cast(float, u);
}
static __device__ __forceinline__ float bf1(unsigned short s) {
    unsigned u = (unsigned)s << 16; return __builtin_bit_cast(float, u);
}
static __device__ __forceinline__ unsigned short f2bf(float f) {
    __hip_bfloat16 b = __float2bfloat16(f);
    return __builtin_bit_cast(unsigned short, b);
}
static __device__ __forceinline__ unsigned packbf(float lo, float hi) {
    return (unsigned)f2bf(lo) | ((unsigned)f2bf(hi) << 16);
}

#define SCAT_CHUNK 4096

// ---------------- weight prep + cnt zero (one launch) ----------------

__global__ __launch_bounds__(256) void wt_all_kernel(const float* __restrict__ W1l,
                                                     const float* __restrict__ W1r,
                                                     const float* __restrict__ W2l,
                                                     const float* __restrict__ W2r,
                                                     unsigned short* __restrict__ T1l,
                                                     unsigned short* __restrict__ T1r,
                                                     unsigned short* __restrict__ T2l,
                                                     unsigned short* __restrict__ T2r,
                                                     int* __restrict__ cnt, int N) {
    int i = blockIdx.x * 256 + threadIdx.x;
    int nthreads = gridDim.x * 256;
    for (int z = i; z < N; z += nthreads) cnt[z] = 0;
    if (i < 16384) {
        int k = i >> 7, n = i & 127;
        T1l[n * 128 + k] = f2bf(W1l[i]);
        T1r[n * 128 + k] = f2bf(W1r[i]);
    } else if (i < 16384 + 8192) {
        int m = i - 16384;
        int k = m >> 6, n = m & 63;
        T2l[n * 128 + k] = f2bf(W2l[m]);
        T2r[n * 128 + k] = f2bf(W2r[m]);
    }
}

// ---------------- MFMA dual GEMM body ----------------
// A[M][128] row-major (fp32 if A_F32 else bf16); WTl/WTr[NC][128] bf16 (=W^T).
// Pl = A@Wl (bf16), Qr = A@Wr (bf16). One wave = 16 output rows.
// mfma_f32_16x16x32_bf16: A lane l -> row l&15, k=(l>>4)*8+j; B lane l ->
// col l&15, same k; D: col=lane&15, row=(lane>>4)*4+reg.

template <int NC, bool A_F32>
static __device__ __forceinline__ void gemm_body(
    int bid, int tid, const void* __restrict__ Av,
    const unsigned short* __restrict__ WTl,
    const unsigned short* __restrict__ WTr,
    unsigned short* __restrict__ Pl,
    unsigned short* __restrict__ Qr, int M) {
    const int wave = tid >> 6;
    const int lane = tid & 63;
    const int m0 = bid * 64 + wave * 16;
    const int lr = lane & 15;
    const int lk = lane >> 4;

    int arow = m0 + lr;
    if (arow >= M) arow = M - 1;

    bf16x8 af[4];
    if (A_F32) {
        const float* Ab = (const float*)Av + (size_t)arow * 128 + lk * 8;
#pragma unroll
        for (int s = 0; s < 4; ++s) {
            float4 v0 = *(const float4*)(Ab + s * 32);
            float4 v1 = *(const float4*)(Ab + s * 32 + 4);
            unsigned short t[8] = {f2bf(v0.x), f2bf(v0.y), f2bf(v0.z), f2bf(v0.w),
                                   f2bf(v1.x), f2bf(v1.y), f2bf(v1.z), f2bf(v1.w)};
            af[s] = *(const bf16x8*)t;
        }
    } else {
        const unsigned short* Ab = (const unsigned short*)Av + (size_t)arow * 128 + lk * 8;
#pragma unroll
        for (int s = 0; s < 4; ++s) af[s] = *(const bf16x8*)(Ab + s * 32);
    }

#pragma unroll
    for (int ct = 0; ct < NC / 16; ++ct) {
        const unsigned short* Bl = WTl + (size_t)(ct * 16 + lr) * 128 + lk * 8;
        const unsigned short* Br = WTr + (size_t)(ct * 16 + lr) * 128 + lk * 8;
        f32x4 accL = {0.f, 0.f, 0.f, 0.f};
        f32x4 accR = {0.f, 0.f, 0.f, 0.f};
#pragma unroll
        for (int s = 0; s < 4; ++s) {
            bf16x8 bl = *(const bf16x8*)(Bl + s * 32);
            bf16x8 br = *(const bf16x8*)(Br + s * 32);
            accL = __builtin_amdgcn_mfma_f32_16x16x32_bf16(af[s], bl, accL, 0, 0, 0);
            accR = __builtin_amdgcn_mfma_f32_16x16x32_bf16(af[s], br, accR, 0, 0, 0);
        }
#pragma unroll
        for (int r = 0; r < 4; ++r) {
            int gr = m0 + lk * 4 + r;
            if (gr < M) {
                Pl[(size_t)gr * NC + ct * 16 + lr] = f2bf(accL[r]);
                Qr[(size_t)gr * NC + ct * 16 + lr] = f2bf(accR[r]);
            }
        }
    }
}

// ---------------- fused GEMM-1 + count_rank ----------------
// Blocks [0, nGemmWg): p = x@W1_l, q = x@W1_r (fp32 A, fused cvt).
// Blocks [nGemmWg, ...): count. Each thread owns 4 consecutive edges ->
// rank ushort4 store has a single writer per cache line. Independent work
// sharing one dispatch slot (count hides under the GEMM).

__global__ __launch_bounds__(256) void gemm1_count_kernel(
    const float* __restrict__ x,
    const unsigned short* __restrict__ wt1l,
    const unsigned short* __restrict__ wt1r,
    unsigned short* __restrict__ Pl,
    unsigned short* __restrict__ Qr, int M,
    const int* __restrict__ dst, int* __restrict__ cnt,
    unsigned short* __restrict__ rank, int E, int nGemmWg) {
    const int tid = threadIdx.x;
    if ((int)blockIdx.x < nGemmWg) {
        gemm_body<128, true>(blockIdx.x, tid, x, wt1l, wt1r, Pl, Qr, M);
    } else {
        int base = ((blockIdx.x - nGemmWg) * 256 + tid) * 4;
        if (base >= E) return;
        int4 d4 = *(const int4*)(dst + base);
        ushort4 r;
        r.x = (unsigned short)atomicAdd(&cnt[d4.x], 1);
        r.y = (unsigned short)atomicAdd(&cnt[d4.y], 1);
        r.z = (unsigned short)atomicAdd(&cnt[d4.z], 1);
        r.w = (unsigned short)atomicAdd(&cnt[d4.w], 1);
        *(ushort4*)(rank + base) = r;
    }
}

__global__ __launch_bounds__(256) void mfma_dual_gemm2(
    const unsigned short* __restrict__ A,
    const unsigned short* __restrict__ WTl,
    const unsigned short* __restrict__ WTr,
    unsigned short* __restrict__ Pl,
    unsigned short* __restrict__ Qr, int M) {
    gemm_body<64, false>(blockIdx.x, threadIdx.x, A, WTl, WTr, Pl, Qr, M);
}

// ---------------- CSR scan / scatter ----------------

__global__ __launch_bounds__(256) void scan_blocks_kernel(const int* __restrict__ cnt,
                                                          int* __restrict__ row_start,
                                                          int* __restrict__ bsum, int N) {
    __shared__ int lds[256];
    int i = blockIdx.x * 256 + threadIdx.x;
    int v = (i < N) ? cnt[i] : 0;
    lds[threadIdx.x] = v;
    __syncthreads();
    for (int off = 1; off < 256; off <<= 1) {
        int t = (threadIdx.x >= off) ? lds[threadIdx.x - off] : 0;
        __syncthreads();
        lds[threadIdx.x] += t;
        __syncthreads();
    }
    if (i < N) row_start[i] = lds[threadIdx.x] - v;
    if (threadIdx.x == 255) bsum[blockIdx.x] = lds[255];
}

__global__ __launch_bounds__(256) void add_off_kernel(int* __restrict__ row_start,
                                                      const int* __restrict__ bsum,
                                                      int N, int E) {
    __shared__ int lds[256];
    int b = blockIdx.x;
    lds[threadIdx.x] = (threadIdx.x < b) ? bsum[threadIdx.x] : 0;
    __syncthreads();
    for (int off = 128; off > 0; off >>= 1) {
        if (threadIdx.x < off) lds[threadIdx.x] += lds[threadIdx.x + off];
        __syncthreads();
    }
    int prefix = lds[0];
    int i = b * 256 + threadIdx.x;
    if (i < N) row_start[i] += prefix;
    if (b == 0 && threadIdx.x == 0) row_start[N] = E;
}

__global__ __launch_bounds__(256) void scatter_kernel(const int* __restrict__ src,
                                                      const int* __restrict__ dst,
                                                      const unsigned short* __restrict__ rank,
                                                      const int* __restrict__ row_start,
                                                      int* __restrict__ csr_src,
                                                      int E, int N) {
    const int j = blockIdx.x & 7;
    const int chunk = blockIdx.x >> 3;
    const int sliceW = (N + 7) >> 3;
    const int lo = j * sliceW;
    const int hi = min(N, lo + sliceW);
    const int base = chunk * SCAT_CHUNK;
    const int end = min(E, base + SCAT_CHUNK);
    for (int e = base + threadIdx.x * 4; e < end; e += 1024) {
        int4 d4 = *(const int4*)(dst + e);
        ushort4 r4 = *(const ushort4*)(rank + e);
        int4 s4 = *(const int4*)(src + e);
        if (d4.x >= lo && d4.x < hi) csr_src[row_start[d4.x] + (int)r4.x] = s4.x;
        if (d4.y >= lo && d4.y < hi) csr_src[row_start[d4.y] + (int)r4.y] = s4.y;
        if (d4.z >= lo && d4.z < hi) csr_src[row_start[d4.z] + (int)r4.z] = s4.z;
        if (d4.w >= lo && d4.w < hi) csr_src[row_start[d4.w] + (int)r4.w] = s4.w;
    }
}

// ---------------- aggregation ----------------
// layer 1: h[n] = relu( mean(p[src]) + q[n] + b1 ); p,q,h bf16; 128 ch.
// 16 nodes/block; 4 nodes per wave, 16 lanes/node, 8 ch (16B) per lane.
__global__ __launch_bounds__(256) void agg1_kernel(const unsigned short* __restrict__ p,
                                                   const unsigned short* __restrict__ q,
                                                   const float* __restrict__ b1,
                                                   const int* __restrict__ row_start,
                                                   const int* __restrict__ csr_src,
                                                   unsigned short* __restrict__ h, int N) {
    int tid = threadIdx.x;
    int n = blockIdx.x * 16 + (tid >> 4);
    int lane = tid & 15;
    if (n >= N) return;
    int s0 = row_start[n], s1 = row_start[n + 1];
    float acc[8] = {};
    const unsigned short* pc = p + lane * 8;
    int e = s0;
    for (; e + 3 < s1; e += 4) {
        uint4 v0 = *(const uint4*)(pc + (size_t)csr_src[e]     * 128);
        uint4 v1 = *(const uint4*)(pc + (size_t)csr_src[e + 1] * 128);
        uint4 v2 = *(const uint4*)(pc + (size_t)csr_src[e + 2] * 128);
        uint4 v3 = *(const uint4*)(pc + (size_t)csr_src[e + 3] * 128);
        acc[0] += (bf_lo(v0.x) + bf_lo(v1.x)) + (bf_lo(v2.x) + bf_lo(v3.x));
        acc[1] += (bf_hi(v0.x) + bf_hi(v1.x)) + (bf_hi(v2.x) + bf_hi(v3.x));
        acc[2] += (bf_lo(v0.y) + bf_lo(v1.y)) + (bf_lo(v2.y) + bf_lo(v3.y));
        acc[3] += (bf_hi(v0.y) + bf_hi(v1.y)) + (bf_hi(v2.y) + bf_hi(v3.y));
        acc[4] += (bf_lo(v0.z) + bf_lo(v1.z)) + (bf_lo(v2.z) + bf_lo(v3.z));
        acc[5] += (bf_hi(v0.z) + bf_hi(v1.z)) + (bf_hi(v2.z) + bf_hi(v3.z));
        acc[6] += (bf_lo(v0.w) + bf_lo(v1.w)) + (bf_lo(v2.w) + bf_lo(v3.w));
        acc[7] += (bf_hi(v0.w) + bf_hi(v1.w)) + (bf_hi(v2.w) + bf_hi(v3.w));
    }
    for (; e < s1; ++e) {
        uint4 v0 = *(const uint4*)(pc + (size_t)csr_src[e] * 128);
        acc[0] += bf_lo(v0.x); acc[1] += bf_hi(v0.x);
        acc[2] += bf_lo(v0.y); acc[3] += bf_hi(v0.y);
        acc[4] += bf_lo(v0.z); acc[5] += bf_hi(v0.z);
        acc[6] += bf_lo(v0.w); acc[7] += bf_hi(v0.w);
    }
    float inv = 1.0f / (float)max(s1 - s0, 1);
    uint4 qv = *(const uint4*)(q + (size_t)n * 128 + lane * 8);
    float4 ba = *(const float4*)(b1 + lane * 8);
    float4 bb = *(const float4*)(b1 + lane * 8 + 4);
    float hv[8];
    hv[0] = fmaxf(fmaf(acc[0], inv, bf_lo(qv.x) + ba.x), 0.f);
    hv[1] = fmaxf(fmaf(acc[1], inv, bf_hi(qv.x) + ba.y), 0.f);
    hv[2] = fmaxf(fmaf(acc[2], inv, bf_lo(qv.y) + ba.z), 0.f);
    hv[3] = fmaxf(fmaf(acc[3], inv, bf_hi(qv.y) + ba.w), 0.f);
    hv[4] = fmaxf(fmaf(acc[4], inv, bf_lo(qv.z) + bb.x), 0.f);
    hv[5] = fmaxf(fmaf(acc[5], inv, bf_hi(qv.z) + bb.y), 0.f);
    hv[6] = fmaxf(fmaf(acc[6], inv, bf_lo(qv.w) + bb.z), 0.f);
    hv[7] = fmaxf(fmaf(acc[7], inv, bf_hi(qv.w) + bb.w), 0.f);
    uint4 o;
    o.x = packbf(hv[0], hv[1]); o.y = packbf(hv[2], hv[3]);
    o.z = packbf(hv[4], hv[5]); o.w = packbf(hv[6], hv[7]);
    *(uint4*)(h + (size_t)n * 128 + lane * 8) = o;
}

// layer 2: out[n] = mean(g[src]) + r[n] + b2; g,r bf16; out f32; 64 ch.
// 16 nodes/block; 4 nodes per wave, 16 lanes/node, 4 ch (8B) per lane.
__global__ __launch_bounds__(256) void agg2_kernel(const unsigned short* __restrict__ g,
                                                   const unsigned short* __restrict__ r,
                                                   const float* __restrict__ b2,
                                                   const int* __restrict__ row_start,
                                                   const int* __restrict__ csr_src,
                                                   float* __restrict__ out, int N) {
    int tid = threadIdx.x;
    int n = blockIdx.x * 16 + (tid >> 4);
    int lane = tid & 15;
    if (n >= N) return;
    int s0 = row_start[n], s1 = row_start[n + 1];
    float acc[4] = {};
    const unsigned short* gc = g + lane * 4;
    int e = s0;
    for (; e + 3 < s1; e += 4) {
        uint2 v0 = *(const uint2*)(gc + (size_t)csr_src[e]     * 64);
        uint2 v1 = *(const uint2*)(gc + (size_t)csr_src[e + 1] * 64);
        uint2 v2 = *(const uint2*)(gc + (size_t)csr_src[e + 2] * 64);
        uint2 v3 = *(const uint2*)(gc + (size_t)csr_src[e + 3] * 64);
        acc[0] += (bf_lo(v0.x) + bf_lo(v1.x)) + (bf_lo(v2.x) + bf_lo(v3.x));
        acc[1] += (bf_hi(v0.x) + bf_hi(v1.x)) + (bf_hi(v2.x) + bf_hi(v3.x));
        acc[2] += (bf_lo(v0.y) + bf_lo(v1.y)) + (bf_lo(v2.y) + bf_lo(v3.y));
        acc[3] += (bf_hi(v0.y) + bf_hi(v1.y)) + (bf_hi(v2.y) + bf_hi(v3.y));
    }
    for (; e < s1; ++e) {
        uint2 v0 = *(const uint2*)(gc + (size_t)csr_src[e] * 64);
        acc[0] += bf_lo(v0.x); acc[1] += bf_hi(v0.x);
        acc[2] += bf_lo(v0.y); acc[3] += bf_hi(v0.y);
    }
    float inv = 1.0f / (float)max(s1 - s0, 1);
    uint2 rv = *(const uint2*)(r + (size_t)n * 64 + lane * 4);
    float4 bb = *(const float4*)(b2 + lane * 4);
    float4 o;
    o.x = fmaf(acc[0], inv, bf_lo(rv.x) + bb.x);
    o.y = fmaf(acc[1], inv, bf_hi(rv.x) + bb.y);
    o.z = fmaf(acc[2], inv, bf_lo(rv.y) + bb.z);
    o.w = fmaf(acc[3], inv, bf_hi(rv.y) + bb.w);
    *(float4*)(out + (size_t)n * 64 + lane * 4) = o;
}

// ---------------------------------------------------------------------------

extern "C" void kernel_launch(void* const* d_in, const int* in_sizes, int n_in,
                              void* d_out, int out_size, void* d_ws, size_t ws_size,
                              hipStream_t stream) {
    const float* x    = (const float*)d_in[0];
    const int*   ei   = (const int*)d_in[1];
    const float* W1_l = (const float*)d_in[2];
    const float* b1   = (const float*)d_in[3];
    const float* W1_r = (const float*)d_in[4];
    const float* W2_l = (const float*)d_in[5];
    const float* b2   = (const float*)d_in[6];
    const float* W2_r = (const float*)d_in[7];

    const int N = in_sizes[0] / 128;   // 50000
    const int E = in_sizes[1] / 2;     // 800000
    const int* e_src = ei;
    const int* e_dst = ei + E;

    // ---- workspace layout ----
    char* ws = (char*)d_ws;
    auto align256 = [](size_t v) { return (v + 255) & ~(size_t)255; };
    size_t off = 0;
    int* row_start = (int*)(ws + off); off += align256((size_t)(N + 1) * 4);
    int* cnt       = (int*)(ws + off); off += align256((size_t)N * 4);
    int* bsum      = (int*)(ws + off); off += align256(1024);
    unsigned short* rank = (unsigned short*)(ws + off); off += align256((size_t)E * 2);
    int* csr_src   = (int*)(ws + off); off += align256((size_t)E * 4);
    unsigned short* h_bf  = (unsigned short*)(ws + off); off += align256((size_t)N * 128 * 2);
    unsigned short* pg_bf = (unsigned short*)(ws + off); off += align256((size_t)N * 128 * 2);
    unsigned short* qr_bf = (unsigned short*)(ws + off); off += align256((size_t)N * 128 * 2);
    unsigned short* wt1l  = (unsigned short*)(ws + off); off += align256(128 * 128 * 2);
    unsigned short* wt1r  = (unsigned short*)(ws + off); off += align256(128 * 128 * 2);
    unsigned short* wt2l  = (unsigned short*)(ws + off); off += align256(128 * 64 * 2);
    unsigned short* wt2r  = (unsigned short*)(ws + off); off += align256(128 * 64 * 2);
    float* out = (float*)d_out;

    const int nb = (N + 255) / 256;
    const int nGemmWg = (N + 63) / 64;
    const int nCountWg = (E / 4 + 255) / 256;
    const int nScatWg = ((E + SCAT_CHUNK - 1) / SCAT_CHUNK) * 8;

    // ---- weight prep + cnt zero ----
    wt_all_kernel<<<128, 256, 0, stream>>>(W1_l, W1_r, W2_l, W2_r,
                                           wt1l, wt1r, wt2l, wt2r, cnt, N);
    // ---- GEMM-1 (p,q) overlapped with count_rank ----
    gemm1_count_kernel<<<nGemmWg + nCountWg, 256, 0, stream>>>(
        x, wt1l, wt1r, pg_bf, qr_bf, N, e_dst, cnt, rank, E, nGemmWg);
    // ---- CSR finish ----
    scan_blocks_kernel<<<nb, 256, 0, stream>>>(cnt, row_start, bsum, N);
    add_off_kernel<<<nb, 256, 0, stream>>>(row_start, bsum, N, E);
    scatter_kernel<<<nScatWg, 256, 0, stream>>>(e_src, e_dst, rank, row_start,
                                                csr_src, E, N);
    // ---- layer 1 aggregate ----
    agg1_kernel<<<(N + 15) / 16, 256, 0, stream>>>(pg_bf, qr_bf, b1, row_start,
                                                   csr_src, h_bf, N);
    // ---- layer 2 ----
    mfma_dual_gemm2<<<(N + 63) / 64, 256, 0, stream>>>(h_bf, wt2l, wt2r,
                                                       pg_bf, qr_bf, N);
    agg2_kernel<<<(N + 15) / 16, 256, 0, stream>>>(pg_bf, qr_bf, b2, row_start,
                                                   csr_src, out, N);
}

// Round 8
// 155.334 us; speedup vs baseline: 2.3449x; 1.0575x over previous
//
#include <hip/hip_runtime.h>
#include <hip/hip_bf16.h>

// ---------------------------------------------------------------------------
// GraphSAGE 2-layer forward.
//   h   = relu( mean_agg(x) @ W1_l + b1 + x @ W1_r )
//   out =       mean_agg(h) @ W2_l + b2 + h @ W2_r
// agg(x)@W == agg(x@W): transform-then-aggregate.
// bf16 MFMA GEMMs; bf16 gather buffers (p,g) and addends (q,r); fp32 out.
// CSR build with ZERO global atomics (far atomics were 800K HBM RMWs):
//   hist:    8 node-ranges (6250 nodes, 25KB LDS hist) x 32 edge-stripes;
//            LDS-atomic counting, private full-line global writes. Fused
//            into the GEMM-1 dispatch (independent work).
//   scan16:  cnt[n] = sum_j hist[r][j][n], block scan -> row_start.
//   add_off_base: global prefix; hist converted IN PLACE to absolute
//            per-(range,stripe,node) cursors.
//   scatter: block (r,j): cursors -> LDS, ds_add_rtn gives position, plain
//            stores into range-r's contiguous csr region (XCD-local via
//            blockIdx&7 == r round-robin placement heuristic).
// ---------------------------------------------------------------------------

typedef __attribute__((ext_vector_type(8))) short bf16x8;
typedef __attribute__((ext_vector_type(4))) float f32x4;

static __device__ __forceinline__ float bf_lo(unsigned u) {
    u <<= 16; return __builtin_bit_cast(float, u);
}
static __device__ __forceinline__ float bf_hi(unsigned u) {
    u &= 0xffff0000u; return __builtin_bit_cast(float, u);
}
static __device__ __forceinline__ unsigned short f2bf(float f) {
    __hip_bfloat16 b = __float2bfloat16(f);
    return __builtin_bit_cast(unsigned short, b);
}
static __device__ __forceinline__ unsigned packbf(float lo, float hi) {
    return (unsigned)f2bf(lo) | ((unsigned)f2bf(hi) << 16);
}

#define NRANGE  8
#define RANGE_W 6250       // ceil(50000/8); N == 8*6250 exactly
#define NSTRIPE 32

// ---------------- weight prep ----------------

__global__ __launch_bounds__(256) void wt_all_kernel(const float* __restrict__ W1l,
                                                     const float* __restrict__ W1r,
                                                     const float* __restrict__ W2l,
                                                     const float* __restrict__ W2r,
                                                     unsigned short* __restrict__ T1l,
                                                     unsigned short* __restrict__ T1r,
                                                     unsigned short* __restrict__ T2l,
                                                     unsigned short* __restrict__ T2r) {
    int i = blockIdx.x * 256 + threadIdx.x;
    if (i < 16384) {
        int k = i >> 7, n = i & 127;
        T1l[n * 128 + k] = f2bf(W1l[i]);
        T1r[n * 128 + k] = f2bf(W1r[i]);
    } else if (i < 16384 + 8192) {
        int m = i - 16384;
        int k = m >> 6, n = m & 63;
        T2l[n * 128 + k] = f2bf(W2l[m]);
        T2r[n * 128 + k] = f2bf(W2r[m]);
    }
}

// ---------------- MFMA dual GEMM body ----------------
// A[M][128] row-major (fp32 if A_F32 else bf16); WTl/WTr[NC][128] bf16 (=W^T).
// Pl = A@Wl (bf16), Qr = A@Wr (bf16). One wave = 16 output rows.
// mfma_f32_16x16x32_bf16: A lane l -> row l&15, k=(l>>4)*8+j; B lane l ->
// col l&15, same k; D: col=lane&15, row=(lane>>4)*4+reg.

template <int NC, bool A_F32>
static __device__ __forceinline__ void gemm_body(
    int bid, int tid, const void* __restrict__ Av,
    const unsigned short* __restrict__ WTl,
    const unsigned short* __restrict__ WTr,
    unsigned short* __restrict__ Pl,
    unsigned short* __restrict__ Qr, int M) {
    const int wave = tid >> 6;
    const int lane = tid & 63;
    const int m0 = bid * 64 + wave * 16;
    const int lr = lane & 15;
    const int lk = lane >> 4;

    int arow = m0 + lr;
    if (arow >= M) arow = M - 1;

    bf16x8 af[4];
    if (A_F32) {
        const float* Ab = (const float*)Av + (size_t)arow * 128 + lk * 8;
#pragma unroll
        for (int s = 0; s < 4; ++s) {
            float4 v0 = *(const float4*)(Ab + s * 32);
            float4 v1 = *(const float4*)(Ab + s * 32 + 4);
            unsigned short t[8] = {f2bf(v0.x), f2bf(v0.y), f2bf(v0.z), f2bf(v0.w),
                                   f2bf(v1.x), f2bf(v1.y), f2bf(v1.z), f2bf(v1.w)};
            af[s] = *(const bf16x8*)t;
        }
    } else {
        const unsigned short* Ab = (const unsigned short*)Av + (size_t)arow * 128 + lk * 8;
#pragma unroll
        for (int s = 0; s < 4; ++s) af[s] = *(const bf16x8*)(Ab + s * 32);
    }

#pragma unroll
    for (int ct = 0; ct < NC / 16; ++ct) {
        const unsigned short* Bl = WTl + (size_t)(ct * 16 + lr) * 128 + lk * 8;
        const unsigned short* Br = WTr + (size_t)(ct * 16 + lr) * 128 + lk * 8;
        f32x4 accL = {0.f, 0.f, 0.f, 0.f};
        f32x4 accR = {0.f, 0.f, 0.f, 0.f};
#pragma unroll
        for (int s = 0; s < 4; ++s) {
            bf16x8 bl = *(const bf16x8*)(Bl + s * 32);
            bf16x8 br = *(const bf16x8*)(Br + s * 32);
            accL = __builtin_amdgcn_mfma_f32_16x16x32_bf16(af[s], bl, accL, 0, 0, 0);
            accR = __builtin_amdgcn_mfma_f32_16x16x32_bf16(af[s], br, accR, 0, 0, 0);
        }
#pragma unroll
        for (int r = 0; r < 4; ++r) {
            int gr = m0 + lk * 4 + r;
            if (gr < M) {
                Pl[(size_t)gr * NC + ct * 16 + lr] = f2bf(accL[r]);
                Qr[(size_t)gr * NC + ct * 16 + lr] = f2bf(accR[r]);
            }
        }
    }
}

// ---------------- fused GEMM-1 + hist ----------------
// Blocks [0, nGemmWg): p = x@W1_l, q = x@W1_r (fp32 A, fused cvt).
// Blocks [nGemmWg, +NRANGE*NSTRIPE): LDS-histogram of dst for (range, stripe).

__global__ __launch_bounds__(256) void gemm1_hist_kernel(
    const float* __restrict__ x,
    const unsigned short* __restrict__ wt1l,
    const unsigned short* __restrict__ wt1r,
    unsigned short* __restrict__ Pl,
    unsigned short* __restrict__ Qr, int M,
    const int* __restrict__ dst, int* __restrict__ hist,
    int E, int N, int nGemmWg) {
    __shared__ int lhist[RANGE_W];
    const int tid = threadIdx.x;
    if ((int)blockIdx.x < nGemmWg) {
        gemm_body<128, true>(blockIdx.x, tid, x, wt1l, wt1r, Pl, Qr, M);
        return;
    }
    const int b = blockIdx.x - nGemmWg;
    const int r = b & (NRANGE - 1);
    const int j = b >> 3;
    const int lo = r * RANGE_W;
    const int w = min(N - lo, RANGE_W);
    for (int i = tid; i < RANGE_W; i += 256) lhist[i] = 0;
    __syncthreads();
    const int stripe = E / NSTRIPE;
    const int s0 = j * stripe;
    const int s1 = (j == NSTRIPE - 1) ? E : s0 + stripe;
    for (int e = s0 + tid * 4; e < s1; e += 1024) {
        int4 d4 = *(const int4*)(dst + e);
        int a0 = d4.x - lo, a1 = d4.y - lo, a2 = d4.z - lo, a3 = d4.w - lo;
        if ((unsigned)a0 < (unsigned)w) atomicAdd(&lhist[a0], 1);
        if ((unsigned)a1 < (unsigned)w) atomicAdd(&lhist[a1], 1);
        if ((unsigned)a2 < (unsigned)w) atomicAdd(&lhist[a2], 1);
        if ((unsigned)a3 < (unsigned)w) atomicAdd(&lhist[a3], 1);
    }
    __syncthreads();
    int* gh = hist + ((size_t)r * NSTRIPE + j) * RANGE_W;
    for (int i = tid; i < RANGE_W; i += 256) gh[i] = lhist[i];
}

// ---------------- CSR scan ----------------
// cnt[i] = sum_j hist[r][j][loc]; per-block exclusive scan -> row_start.

__global__ __launch_bounds__(256) void scan16_kernel(const int* __restrict__ hist,
                                                     int* __restrict__ row_start,
                                                     int* __restrict__ bsum, int N) {
    __shared__ int lds[256];
    int i = blockIdx.x * 256 + threadIdx.x;
    int v = 0;
    if (i < N) {
        int r = i / RANGE_W, loc = i - r * RANGE_W;
        const int* hp = hist + (size_t)r * NSTRIPE * RANGE_W + loc;
#pragma unroll
        for (int j = 0; j < NSTRIPE; ++j) v += hp[j * RANGE_W];
    }
    lds[threadIdx.x] = v;
    __syncthreads();
    for (int off = 1; off < 256; off <<= 1) {
        int t = (threadIdx.x >= off) ? lds[threadIdx.x - off] : 0;
        __syncthreads();
        lds[threadIdx.x] += t;
        __syncthreads();
    }
    if (i < N) row_start[i] = lds[threadIdx.x] - v;
    if (threadIdx.x == 255) bsum[blockIdx.x] = lds[255];
}

// global prefix via bsum reduce; row_start finalized; hist -> absolute
// cursors in place: hist[r][j][loc] = row_start[n] + sum_{j'<j} hist[r][j'].
__global__ __launch_bounds__(256) void add_off_base_kernel(int* __restrict__ row_start,
                                                           const int* __restrict__ bsum,
                                                           int* __restrict__ hist,
                                                           int N, int E) {
    __shared__ int lds[256];
    int b = blockIdx.x;
    lds[threadIdx.x] = (threadIdx.x < b) ? bsum[threadIdx.x] : 0;
    __syncthreads();
    for (int off = 128; off > 0; off >>= 1) {
        if (threadIdx.x < off) lds[threadIdx.x] += lds[threadIdx.x + off];
        __syncthreads();
    }
    int prefix = lds[0];
    int i = b * 256 + threadIdx.x;
    if (i < N) {
        int s = row_start[i] + prefix;
        row_start[i] = s;
        int r = i / RANGE_W, loc = i - r * RANGE_W;
        int* hp = hist + (size_t)r * NSTRIPE * RANGE_W + loc;
#pragma unroll
        for (int j = 0; j < NSTRIPE; ++j) {
            int h = hp[j * RANGE_W];
            hp[j * RANGE_W] = s;
            s += h;
        }
    }
    if (b == 0 && threadIdx.x == 0) row_start[N] = E;
}

// ---------------- scatter (LDS cursors, no global atomics) ----------------

__global__ __launch_bounds__(256) void scatter_lds_kernel(const int* __restrict__ src,
                                                          const int* __restrict__ dst,
                                                          const int* __restrict__ base,
                                                          int* __restrict__ csr_src,
                                                          int E, int N) {
    __shared__ int lcur[RANGE_W];
    const int tid = threadIdx.x;
    const int b = blockIdx.x;
    const int r = b & (NRANGE - 1);
    const int j = b >> 3;
    const int lo = r * RANGE_W;
    const int w = min(N - lo, RANGE_W);
    const int* gb = base + ((size_t)r * NSTRIPE + j) * RANGE_W;
    for (int i = tid; i < w; i += 256) lcur[i] = gb[i];
    __syncthreads();
    const int stripe = E / NSTRIPE;
    const int s0 = j * stripe;
    const int s1 = (j == NSTRIPE - 1) ? E : s0 + stripe;
    for (int e = s0 + tid * 4; e < s1; e += 1024) {
        int4 d4 = *(const int4*)(dst + e);
        int4 v4 = *(const int4*)(src + e);
        int a0 = d4.x - lo, a1 = d4.y - lo, a2 = d4.z - lo, a3 = d4.w - lo;
        if ((unsigned)a0 < (unsigned)w) { int p = atomicAdd(&lcur[a0], 1); csr_src[p] = v4.x; }
        if ((unsigned)a1 < (unsigned)w) { int p = atomicAdd(&lcur[a1], 1); csr_src[p] = v4.y; }
        if ((unsigned)a2 < (unsigned)w) { int p = atomicAdd(&lcur[a2], 1); csr_src[p] = v4.z; }
        if ((unsigned)a3 < (unsigned)w) { int p = atomicAdd(&lcur[a3], 1); csr_src[p] = v4.w; }
    }
}

__global__ __launch_bounds__(256) void mfma_dual_gemm2(
    const unsigned short* __restrict__ A,
    const unsigned short* __restrict__ WTl,
    const unsigned short* __restrict__ WTr,
    unsigned short* __restrict__ Pl,
    unsigned short* __restrict__ Qr, int M) {
    gemm_body<64, false>(blockIdx.x, threadIdx.x, A, WTl, WTr, Pl, Qr, M);
}

// ---------------- aggregation ----------------
// layer 1: h[n] = relu( mean(p[src]) + q[n] + b1 ); p,q,h bf16; 128 ch.
// 16 nodes/block; 4 nodes per wave, 16 lanes/node, 8 ch (16B) per lane.
__global__ __launch_bounds__(256) void agg1_kernel(const unsigned short* __restrict__ p,
                                                   const unsigned short* __restrict__ q,
                                                   const float* __restrict__ b1,
                                                   const int* __restrict__ row_start,
                                                   const int* __restrict__ csr_src,
                                                   unsigned short* __restrict__ h, int N) {
    int tid = threadIdx.x;
    int n = blockIdx.x * 16 + (tid >> 4);
    int lane = tid & 15;
    if (n >= N) return;
    int s0 = row_start[n], s1 = row_start[n + 1];
    float acc[8] = {};
    const unsigned short* pc = p + lane * 8;
    int e = s0;
    for (; e + 3 < s1; e += 4) {
        uint4 v0 = *(const uint4*)(pc + (size_t)csr_src[e]     * 128);
        uint4 v1 = *(const uint4*)(pc + (size_t)csr_src[e + 1] * 128);
        uint4 v2 = *(const uint4*)(pc + (size_t)csr_src[e + 2] * 128);
        uint4 v3 = *(const uint4*)(pc + (size_t)csr_src[e + 3] * 128);
        acc[0] += (bf_lo(v0.x) + bf_lo(v1.x)) + (bf_lo(v2.x) + bf_lo(v3.x));
        acc[1] += (bf_hi(v0.x) + bf_hi(v1.x)) + (bf_hi(v2.x) + bf_hi(v3.x));
        acc[2] += (bf_lo(v0.y) + bf_lo(v1.y)) + (bf_lo(v2.y) + bf_lo(v3.y));
        acc[3] += (bf_hi(v0.y) + bf_hi(v1.y)) + (bf_hi(v2.y) + bf_hi(v3.y));
        acc[4] += (bf_lo(v0.z) + bf_lo(v1.z)) + (bf_lo(v2.z) + bf_lo(v3.z));
        acc[5] += (bf_hi(v0.z) + bf_hi(v1.z)) + (bf_hi(v2.z) + bf_hi(v3.z));
        acc[6] += (bf_lo(v0.w) + bf_lo(v1.w)) + (bf_lo(v2.w) + bf_lo(v3.w));
        acc[7] += (bf_hi(v0.w) + bf_hi(v1.w)) + (bf_hi(v2.w) + bf_hi(v3.w));
    }
    for (; e < s1; ++e) {
        uint4 v0 = *(const uint4*)(pc + (size_t)csr_src[e] * 128);
        acc[0] += bf_lo(v0.x); acc[1] += bf_hi(v0.x);
        acc[2] += bf_lo(v0.y); acc[3] += bf_hi(v0.y);
        acc[4] += bf_lo(v0.z); acc[5] += bf_hi(v0.z);
        acc[6] += bf_lo(v0.w); acc[7] += bf_hi(v0.w);
    }
    float inv = 1.0f / (float)max(s1 - s0, 1);
    uint4 qv = *(const uint4*)(q + (size_t)n * 128 + lane * 8);
    float4 ba = *(const float4*)(b1 + lane * 8);
    float4 bb = *(const float4*)(b1 + lane * 8 + 4);
    float hv[8];
    hv[0] = fmaxf(fmaf(acc[0], inv, bf_lo(qv.x) + ba.x), 0.f);
    hv[1] = fmaxf(fmaf(acc[1], inv, bf_hi(qv.x) + ba.y), 0.f);
    hv[2] = fmaxf(fmaf(acc[2], inv, bf_lo(qv.y) + ba.z), 0.f);
    hv[3] = fmaxf(fmaf(acc[3], inv, bf_hi(qv.y) + ba.w), 0.f);
    hv[4] = fmaxf(fmaf(acc[4], inv, bf_lo(qv.z) + bb.x), 0.f);
    hv[5] = fmaxf(fmaf(acc[5], inv, bf_hi(qv.z) + bb.y), 0.f);
    hv[6] = fmaxf(fmaf(acc[6], inv, bf_lo(qv.w) + bb.z), 0.f);
    hv[7] = fmaxf(fmaf(acc[7], inv, bf_hi(qv.w) + bb.w), 0.f);
    uint4 o;
    o.x = packbf(hv[0], hv[1]); o.y = packbf(hv[2], hv[3]);
    o.z = packbf(hv[4], hv[5]); o.w = packbf(hv[6], hv[7]);
    *(uint4*)(h + (size_t)n * 128 + lane * 8) = o;
}

// layer 2: out[n] = mean(g[src]) + r[n] + b2; g,r bf16; out f32; 64 ch.
__global__ __launch_bounds__(256) void agg2_kernel(const unsigned short* __restrict__ g,
                                                   const unsigned short* __restrict__ r,
                                                   const float* __restrict__ b2,
                                                   const int* __restrict__ row_start,
                                                   const int* __restrict__ csr_src,
                                                   float* __restrict__ out, int N) {
    int tid = threadIdx.x;
    int n = blockIdx.x * 16 + (tid >> 4);
    int lane = tid & 15;
    if (n >= N) return;
    int s0 = row_start[n], s1 = row_start[n + 1];
    float acc[4] = {};
    const unsigned short* gc = g + lane * 4;
    int e = s0;
    for (; e + 3 < s1; e += 4) {
        uint2 v0 = *(const uint2*)(gc + (size_t)csr_src[e]     * 64);
        uint2 v1 = *(const uint2*)(gc + (size_t)csr_src[e + 1] * 64);
        uint2 v2 = *(const uint2*)(gc + (size_t)csr_src[e + 2] * 64);
        uint2 v3 = *(const uint2*)(gc + (size_t)csr_src[e + 3] * 64);
        acc[0] += (bf_lo(v0.x) + bf_lo(v1.x)) + (bf_lo(v2.x) + bf_lo(v3.x));
        acc[1] += (bf_hi(v0.x) + bf_hi(v1.x)) + (bf_hi(v2.x) + bf_hi(v3.x));
        acc[2] += (bf_lo(v0.y) + bf_lo(v1.y)) + (bf_lo(v2.y) + bf_lo(v3.y));
        acc[3] += (bf_hi(v0.y) + bf_hi(v1.y)) + (bf_hi(v2.y) + bf_hi(v3.y));
    }
    for (; e < s1; ++e) {
        uint2 v0 = *(const uint2*)(gc + (size_t)csr_src[e] * 64);
        acc[0] += bf_lo(v0.x); acc[1] += bf_hi(v0.x);
        acc[2] += bf_lo(v0.y); acc[3] += bf_hi(v0.y);
    }
    float inv = 1.0f / (float)max(s1 - s0, 1);
    uint2 rv = *(const uint2*)(r + (size_t)n * 64 + lane * 4);
    float4 bb = *(const float4*)(b2 + lane * 4);
    float4 o;
    o.x = fmaf(acc[0], inv, bf_lo(rv.x) + bb.x);
    o.y = fmaf(acc[1], inv, bf_hi(rv.x) + bb.y);
    o.z = fmaf(acc[2], inv, bf_lo(rv.y) + bb.z);
    o.w = fmaf(acc[3], inv, bf_hi(rv.y) + bb.w);
    *(float4*)(out + (size_t)n * 64 + lane * 4) = o;
}

// ---------------------------------------------------------------------------

extern "C" void kernel_launch(void* const* d_in, const int* in_sizes, int n_in,
                              void* d_out, int out_size, void* d_ws, size_t ws_size,
                              hipStream_t stream) {
    const float* x    = (const float*)d_in[0];
    const int*   ei   = (const int*)d_in[1];
    const float* W1_l = (const float*)d_in[2];
    const float* b1   = (const float*)d_in[3];
    const float* W1_r = (const float*)d_in[4];
    const float* W2_l = (const float*)d_in[5];
    const float* b2   = (const float*)d_in[6];
    const float* W2_r = (const float*)d_in[7];

    const int N = in_sizes[0] / 128;   // 50000
    const int E = in_sizes[1] / 2;     // 800000
    const int* e_src = ei;
    const int* e_dst = ei + E;

    // ---- workspace layout ----
    char* ws = (char*)d_ws;
    auto align256 = [](size_t v) { return (v + 255) & ~(size_t)255; };
    size_t off = 0;
    int* row_start = (int*)(ws + off); off += align256((size_t)(N + 1) * 4);
    int* bsum      = (int*)(ws + off); off += align256(1024);
    int* hist      = (int*)(ws + off); off += align256((size_t)NRANGE * NSTRIPE * RANGE_W * 4);
    int* csr_src   = (int*)(ws + off); off += align256((size_t)E * 4);
    unsigned short* h_bf  = (unsigned short*)(ws + off); off += align256((size_t)N * 128 * 2);
    unsigned short* pg_bf = (unsigned short*)(ws + off); off += align256((size_t)N * 128 * 2);
    unsigned short* qr_bf = (unsigned short*)(ws + off); off += align256((size_t)N * 128 * 2);
    unsigned short* wt1l  = (unsigned short*)(ws + off); off += align256(128 * 128 * 2);
    unsigned short* wt1r  = (unsigned short*)(ws + off); off += align256(128 * 128 * 2);
    unsigned short* wt2l  = (unsigned short*)(ws + off); off += align256(128 * 64 * 2);
    unsigned short* wt2r  = (unsigned short*)(ws + off); off += align256(128 * 64 * 2);
    float* out = (float*)d_out;

    const int nb = (N + 255) / 256;
    const int nGemmWg = (N + 63) / 64;

    // ---- weight prep ----
    wt_all_kernel<<<(16384 + 8192 + 255) / 256, 256, 0, stream>>>(
        W1_l, W1_r, W2_l, W2_r, wt1l, wt1r, wt2l, wt2r);
    // ---- GEMM-1 (p,q) overlapped with histogram ----
    gemm1_hist_kernel<<<nGemmWg + NRANGE * NSTRIPE, 256, 0, stream>>>(
        x, wt1l, wt1r, pg_bf, qr_bf, N, e_dst, hist, E, N, nGemmWg);
    // ---- CSR finish (no global atomics) ----
    scan16_kernel<<<nb, 256, 0, stream>>>(hist, row_start, bsum, N);
    add_off_base_kernel<<<nb, 256, 0, stream>>>(row_start, bsum, hist, N, E);
    scatter_lds_kernel<<<NRANGE * NSTRIPE, 256, 0, stream>>>(e_src, e_dst, hist,
                                                             csr_src, E, N);
    // ---- layer 1 aggregate ----
    agg1_kernel<<<(N + 15) / 16, 256, 0, stream>>>(pg_bf, qr_bf, b1, row_start,
                                                   csr_src, h_bf, N);
    // ---- layer 2 ----
    mfma_dual_gemm2<<<(N + 63) / 64, 256, 0, stream>>>(h_bf, wt2l, wt2r,
                                                       pg_bf, qr_bf, N);
    agg2_kernel<<<(N + 15) / 16, 256, 0, stream>>>(pg_bf, qr_bf, b2, row_start,
                                                   csr_src, out, N);
}

// Round 9
// 153.807 us; speedup vs baseline: 2.3682x; 1.0099x over previous
//
#include <hip/hip_runtime.h>
#include <hip/hip_bf16.h>

// ---------------------------------------------------------------------------
// GraphSAGE 2-layer forward.
//   h   = relu( mean_agg(x) @ W1_l + b1 + x @ W1_r )
//   out =       mean_agg(h) @ W2_l + b2 + h @ W2_r
// agg(x)@W == agg(x@W): transform-then-aggregate. Biases folded into the
// GEMM epilogue of the root term (q = x@W1_r + b1, r = h@W2_r + b2).
// bf16 MFMA GEMMs; bf16 gather buffers (p,g) and addends (q,r); fp32 out.
// CSR build with ZERO global atomics:
//   hist:    8 node-ranges x 32 edge-stripes; LDS hist PACKED 2 ushort/int
//            (12.5 KB -> no LDS occupancy cap on the fused GEMM blocks).
//   scan16:  cnt[n] = sum_j hist, block scan -> row_start.
//   add_off_base: global prefix; absolute cursors to UNPACKED cur buffer.
//   scatter: block (r,j): cursors -> LDS, ds_add_rtn position, plain stores
//            into range-r's contiguous csr region (blockIdx&7==r -> XCD-local).
// ---------------------------------------------------------------------------

typedef __attribute__((ext_vector_type(8))) short bf16x8;
typedef __attribute__((ext_vector_type(4))) float f32x4;

static __device__ __forceinline__ float bf_lo(unsigned u) {
    u <<= 16; return __builtin_bit_cast(float, u);
}
static __device__ __forceinline__ float bf_hi(unsigned u) {
    u &= 0xffff0000u; return __builtin_bit_cast(float, u);
}
static __device__ __forceinline__ unsigned short f2bf(float f) {
    __hip_bfloat16 b = __float2bfloat16(f);
    return __builtin_bit_cast(unsigned short, b);
}
static __device__ __forceinline__ unsigned packbf(float lo, float hi) {
    return (unsigned)f2bf(lo) | ((unsigned)f2bf(hi) << 16);
}

#define NRANGE   8
#define RANGE_W  6250      // N == 8*6250 exactly
#define PACKED_W 3125      // RANGE_W/2, two ushort counts per int
#define NSTRIPE  32

// ---------------- weight prep ----------------

__global__ __launch_bounds__(256) void wt_all_kernel(const float* __restrict__ W1l,
                                                     const float* __restrict__ W1r,
                                                     const float* __restrict__ W2l,
                                                     const float* __restrict__ W2r,
                                                     unsigned short* __restrict__ T1l,
                                                     unsigned short* __restrict__ T1r,
                                                     unsigned short* __restrict__ T2l,
                                                     unsigned short* __restrict__ T2r) {
    int i = blockIdx.x * 256 + threadIdx.x;
    if (i < 16384) {
        int k = i >> 7, n = i & 127;
        T1l[n * 128 + k] = f2bf(W1l[i]);
        T1r[n * 128 + k] = f2bf(W1r[i]);
    } else if (i < 16384 + 8192) {
        int m = i - 16384;
        int k = m >> 6, n = m & 63;
        T2l[n * 128 + k] = f2bf(W2l[m]);
        T2r[n * 128 + k] = f2bf(W2r[m]);
    }
}

// ---------------- MFMA dual GEMM body ----------------
// A[M][128] row-major (fp32 if A_F32 else bf16); WTl/WTr[NC][128] bf16 (=W^T).
// Pl = A@Wl (bf16), Qr = A@Wr + bias (bf16). One wave = 16 output rows.
// mfma_f32_16x16x32_bf16: A lane l -> row l&15, k=(l>>4)*8+j; B lane l ->
// col l&15, same k; D: col=lane&15, row=(lane>>4)*4+reg.

template <int NC, bool A_F32>
static __device__ __forceinline__ void gemm_body(
    int bid, int tid, const void* __restrict__ Av,
    const unsigned short* __restrict__ WTl,
    const unsigned short* __restrict__ WTr,
    const float* __restrict__ bias,
    unsigned short* __restrict__ Pl,
    unsigned short* __restrict__ Qr, int M) {
    const int wave = tid >> 6;
    const int lane = tid & 63;
    const int m0 = bid * 64 + wave * 16;
    const int lr = lane & 15;
    const int lk = lane >> 4;

    int arow = m0 + lr;
    if (arow >= M) arow = M - 1;

    bf16x8 af[4];
    if (A_F32) {
        const float* Ab = (const float*)Av + (size_t)arow * 128 + lk * 8;
#pragma unroll
        for (int s = 0; s < 4; ++s) {
            float4 v0 = *(const float4*)(Ab + s * 32);
            float4 v1 = *(const float4*)(Ab + s * 32 + 4);
            unsigned short t[8] = {f2bf(v0.x), f2bf(v0.y), f2bf(v0.z), f2bf(v0.w),
                                   f2bf(v1.x), f2bf(v1.y), f2bf(v1.z), f2bf(v1.w)};
            af[s] = *(const bf16x8*)t;
        }
    } else {
        const unsigned short* Ab = (const unsigned short*)Av + (size_t)arow * 128 + lk * 8;
#pragma unroll
        for (int s = 0; s < 4; ++s) af[s] = *(const bf16x8*)(Ab + s * 32);
    }

#pragma unroll
    for (int ct = 0; ct < NC / 16; ++ct) {
        const unsigned short* Bl = WTl + (size_t)(ct * 16 + lr) * 128 + lk * 8;
        const unsigned short* Br = WTr + (size_t)(ct * 16 + lr) * 128 + lk * 8;
        f32x4 accL = {0.f, 0.f, 0.f, 0.f};
        f32x4 accR = {0.f, 0.f, 0.f, 0.f};
#pragma unroll
        for (int s = 0; s < 4; ++s) {
            bf16x8 bl = *(const bf16x8*)(Bl + s * 32);
            bf16x8 br = *(const bf16x8*)(Br + s * 32);
            accL = __builtin_amdgcn_mfma_f32_16x16x32_bf16(af[s], bl, accL, 0, 0, 0);
            accR = __builtin_amdgcn_mfma_f32_16x16x32_bf16(af[s], br, accR, 0, 0, 0);
        }
        float bcol = bias[ct * 16 + lr];
#pragma unroll
        for (int r = 0; r < 4; ++r) {
            int gr = m0 + lk * 4 + r;
            if (gr < M) {
                Pl[(size_t)gr * NC + ct * 16 + lr] = f2bf(accL[r]);
                Qr[(size_t)gr * NC + ct * 16 + lr] = f2bf(accR[r] + bcol);
            }
        }
    }
}

// ---------------- fused GEMM-1 + hist ----------------
// Blocks [0, nGemmWg): p = x@W1_l, q = x@W1_r + b1 (fp32 A, fused cvt).
// Blocks [nGemmWg, +NRANGE*NSTRIPE): packed LDS histogram of dst.

__global__ __launch_bounds__(256) void gemm1_hist_kernel(
    const float* __restrict__ x,
    const unsigned short* __restrict__ wt1l,
    const unsigned short* __restrict__ wt1r,
    const float* __restrict__ b1,
    unsigned short* __restrict__ Pl,
    unsigned short* __restrict__ Qr, int M,
    const int* __restrict__ dst, int* __restrict__ hist,
    int E, int N, int nGemmWg) {
    __shared__ int lhist[PACKED_W];
    const int tid = threadIdx.x;
    if ((int)blockIdx.x < nGemmWg) {
        gemm_body<128, true>(blockIdx.x, tid, x, wt1l, wt1r, b1, Pl, Qr, M);
        return;
    }
    const int b = blockIdx.x - nGemmWg;
    const int r = b & (NRANGE - 1);
    const int j = b >> 3;
    const int lo = r * RANGE_W;
    const int w = min(N - lo, RANGE_W);
    for (int i = tid; i < PACKED_W; i += 256) lhist[i] = 0;
    __syncthreads();
    const int stripe = E / NSTRIPE;
    const int s0 = j * stripe;
    const int s1 = (j == NSTRIPE - 1) ? E : s0 + stripe;
    for (int e = s0 + tid * 4; e < s1; e += 1024) {
        int4 d4 = *(const int4*)(dst + e);
        int a0 = d4.x - lo, a1 = d4.y - lo, a2 = d4.z - lo, a3 = d4.w - lo;
        if ((unsigned)a0 < (unsigned)w) atomicAdd(&lhist[a0 >> 1], 1u << ((a0 & 1) * 16));
        if ((unsigned)a1 < (unsigned)w) atomicAdd(&lhist[a1 >> 1], 1u << ((a1 & 1) * 16));
        if ((unsigned)a2 < (unsigned)w) atomicAdd(&lhist[a2 >> 1], 1u << ((a2 & 1) * 16));
        if ((unsigned)a3 < (unsigned)w) atomicAdd(&lhist[a3 >> 1], 1u << ((a3 & 1) * 16));
    }
    __syncthreads();
    int* gh = hist + ((size_t)r * NSTRIPE + j) * PACKED_W;
    for (int i = tid; i < PACKED_W; i += 256) gh[i] = lhist[i];
}

// ---------------- CSR scan ----------------

__global__ __launch_bounds__(256) void scan16_kernel(const int* __restrict__ hist,
                                                     int* __restrict__ row_start,
                                                     int* __restrict__ bsum, int N) {
    __shared__ int lds[256];
    int i = blockIdx.x * 256 + threadIdx.x;
    int v = 0;
    if (i < N) {
        int r = i / RANGE_W, loc = i - r * RANGE_W;
        const int* hp = hist + (size_t)r * NSTRIPE * PACKED_W + (loc >> 1);
        int sh = (loc & 1) * 16;
#pragma unroll
        for (int j = 0; j < NSTRIPE; ++j) v += (hp[j * PACKED_W] >> sh) & 0xffff;
    }
    lds[threadIdx.x] = v;
    __syncthreads();
    for (int off = 1; off < 256; off <<= 1) {
        int t = (threadIdx.x >= off) ? lds[threadIdx.x - off] : 0;
        __syncthreads();
        lds[threadIdx.x] += t;
        __syncthreads();
    }
    if (i < N) row_start[i] = lds[threadIdx.x] - v;
    if (threadIdx.x == 255) bsum[blockIdx.x] = lds[255];
}

// global prefix via bsum reduce; row_start finalized; absolute per-
// (range,stripe,node) cursors written UNPACKED to cur.
__global__ __launch_bounds__(256) void add_off_base_kernel(int* __restrict__ row_start,
                                                           const int* __restrict__ bsum,
                                                           const int* __restrict__ hist,
                                                           int* __restrict__ cur,
                                                           int N, int E) {
    __shared__ int lds[256];
    int b = blockIdx.x;
    lds[threadIdx.x] = (threadIdx.x < b) ? bsum[threadIdx.x] : 0;
    __syncthreads();
    for (int off = 128; off > 0; off >>= 1) {
        if (threadIdx.x < off) lds[threadIdx.x] += lds[threadIdx.x + off];
        __syncthreads();
    }
    int prefix = lds[0];
    int i = b * 256 + threadIdx.x;
    if (i < N) {
        int s = row_start[i] + prefix;
        row_start[i] = s;
        int r = i / RANGE_W, loc = i - r * RANGE_W;
        const int* hp = hist + (size_t)r * NSTRIPE * PACKED_W + (loc >> 1);
        int* cp = cur + (size_t)r * NSTRIPE * RANGE_W + loc;
        int sh = (loc & 1) * 16;
#pragma unroll
        for (int j = 0; j < NSTRIPE; ++j) {
            int h = (hp[j * PACKED_W] >> sh) & 0xffff;
            cp[j * RANGE_W] = s;
            s += h;
        }
    }
    if (b == 0 && threadIdx.x == 0) row_start[N] = E;
}

// ---------------- scatter (LDS cursors, no global atomics) ----------------

__global__ __launch_bounds__(256) void scatter_lds_kernel(const int* __restrict__ src,
                                                          const int* __restrict__ dst,
                                                          const int* __restrict__ cur,
                                                          int* __restrict__ csr_src,
                                                          int E, int N) {
    __shared__ int lcur[RANGE_W];
    const int tid = threadIdx.x;
    const int b = blockIdx.x;
    const int r = b & (NRANGE - 1);
    const int j = b >> 3;
    const int lo = r * RANGE_W;
    const int w = min(N - lo, RANGE_W);
    const int* gb = cur + ((size_t)r * NSTRIPE + j) * RANGE_W;
    for (int i = tid; i < w; i += 256) lcur[i] = gb[i];
    __syncthreads();
    const int stripe = E / NSTRIPE;
    const int s0 = j * stripe;
    const int s1 = (j == NSTRIPE - 1) ? E : s0 + stripe;
    for (int e = s0 + tid * 4; e < s1; e += 1024) {
        int4 d4 = *(const int4*)(dst + e);
        int4 v4 = *(const int4*)(src + e);
        int a0 = d4.x - lo, a1 = d4.y - lo, a2 = d4.z - lo, a3 = d4.w - lo;
        if ((unsigned)a0 < (unsigned)w) { int p = atomicAdd(&lcur[a0], 1); csr_src[p] = v4.x; }
        if ((unsigned)a1 < (unsigned)w) { int p = atomicAdd(&lcur[a1], 1); csr_src[p] = v4.y; }
        if ((unsigned)a2 < (unsigned)w) { int p = atomicAdd(&lcur[a2], 1); csr_src[p] = v4.z; }
        if ((unsigned)a3 < (unsigned)w) { int p = atomicAdd(&lcur[a3], 1); csr_src[p] = v4.w; }
    }
}

__global__ __launch_bounds__(256) void mfma_dual_gemm2(
    const unsigned short* __restrict__ A,
    const unsigned short* __restrict__ WTl,
    const unsigned short* __restrict__ WTr,
    const float* __restrict__ b2,
    unsigned short* __restrict__ Pl,
    unsigned short* __restrict__ Qr, int M) {
    gemm_body<64, false>(blockIdx.x, threadIdx.x, A, WTl, WTr, b2, Pl, Qr, M);
}

// ---------------- aggregation ----------------
// layer 1: h[n] = relu( mean(p[src]) + q[n] ); p,q,h bf16; 128 ch.
// 16 nodes/block; 4 nodes per wave, 16 lanes/node, 8 ch (16B) per lane.
__global__ __launch_bounds__(256) void agg1_kernel(const unsigned short* __restrict__ p,
                                                   const unsigned short* __restrict__ q,
                                                   const int* __restrict__ row_start,
                                                   const int* __restrict__ csr_src,
                                                   unsigned short* __restrict__ h, int N) {
    int tid = threadIdx.x;
    int n = blockIdx.x * 16 + (tid >> 4);
    int lane = tid & 15;
    if (n >= N) return;
    int s0 = row_start[n], s1 = row_start[n + 1];
    float acc[8] = {};
    const unsigned short* pc = p + lane * 8;
    int e = s0;
    for (; e + 3 < s1; e += 4) {
        uint4 v0 = *(const uint4*)(pc + (size_t)csr_src[e]     * 128);
        uint4 v1 = *(const uint4*)(pc + (size_t)csr_src[e + 1] * 128);
        uint4 v2 = *(const uint4*)(pc + (size_t)csr_src[e + 2] * 128);
        uint4 v3 = *(const uint4*)(pc + (size_t)csr_src[e + 3] * 128);
        acc[0] += (bf_lo(v0.x) + bf_lo(v1.x)) + (bf_lo(v2.x) + bf_lo(v3.x));
        acc[1] += (bf_hi(v0.x) + bf_hi(v1.x)) + (bf_hi(v2.x) + bf_hi(v3.x));
        acc[2] += (bf_lo(v0.y) + bf_lo(v1.y)) + (bf_lo(v2.y) + bf_lo(v3.y));
        acc[3] += (bf_hi(v0.y) + bf_hi(v1.y)) + (bf_hi(v2.y) + bf_hi(v3.y));
        acc[4] += (bf_lo(v0.z) + bf_lo(v1.z)) + (bf_lo(v2.z) + bf_lo(v3.z));
        acc[5] += (bf_hi(v0.z) + bf_hi(v1.z)) + (bf_hi(v2.z) + bf_hi(v3.z));
        acc[6] += (bf_lo(v0.w) + bf_lo(v1.w)) + (bf_lo(v2.w) + bf_lo(v3.w));
        acc[7] += (bf_hi(v0.w) + bf_hi(v1.w)) + (bf_hi(v2.w) + bf_hi(v3.w));
    }
    for (; e < s1; ++e) {
        uint4 v0 = *(const uint4*)(pc + (size_t)csr_src[e] * 128);
        acc[0] += bf_lo(v0.x); acc[1] += bf_hi(v0.x);
        acc[2] += bf_lo(v0.y); acc[3] += bf_hi(v0.y);
        acc[4] += bf_lo(v0.z); acc[5] += bf_hi(v0.z);
        acc[6] += bf_lo(v0.w); acc[7] += bf_hi(v0.w);
    }
    float inv = 1.0f / (float)max(s1 - s0, 1);
    uint4 qv = *(const uint4*)(q + (size_t)n * 128 + lane * 8);
    float hv[8];
    hv[0] = fmaxf(fmaf(acc[0], inv, bf_lo(qv.x)), 0.f);
    hv[1] = fmaxf(fmaf(acc[1], inv, bf_hi(qv.x)), 0.f);
    hv[2] = fmaxf(fmaf(acc[2], inv, bf_lo(qv.y)), 0.f);
    hv[3] = fmaxf(fmaf(acc[3], inv, bf_hi(qv.y)), 0.f);
    hv[4] = fmaxf(fmaf(acc[4], inv, bf_lo(qv.z)), 0.f);
    hv[5] = fmaxf(fmaf(acc[5], inv, bf_hi(qv.z)), 0.f);
    hv[6] = fmaxf(fmaf(acc[6], inv, bf_lo(qv.w)), 0.f);
    hv[7] = fmaxf(fmaf(acc[7], inv, bf_hi(qv.w)), 0.f);
    uint4 o;
    o.x = packbf(hv[0], hv[1]); o.y = packbf(hv[2], hv[3]);
    o.z = packbf(hv[4], hv[5]); o.w = packbf(hv[6], hv[7]);
    *(uint4*)(h + (size_t)n * 128 + lane * 8) = o;
}

// layer 2: out[n] = mean(g[src]) + r[n]; g,r bf16; out f32; 64 ch.
__global__ __launch_bounds__(256) void agg2_kernel(const unsigned short* __restrict__ g,
                                                   const unsigned short* __restrict__ r,
                                                   const int* __restrict__ row_start,
                                                   const int* __restrict__ csr_src,
                                                   float* __restrict__ out, int N) {
    int tid = threadIdx.x;
    int n = blockIdx.x * 16 + (tid >> 4);
    int lane = tid & 15;
    if (n >= N) return;
    int s0 = row_start[n], s1 = row_start[n + 1];
    float acc[4] = {};
    const unsigned short* gc = g + lane * 4;
    int e = s0;
    for (; e + 3 < s1; e += 4) {
        uint2 v0 = *(const uint2*)(gc + (size_t)csr_src[e]     * 64);
        uint2 v1 = *(const uint2*)(gc + (size_t)csr_src[e + 1] * 64);
        uint2 v2 = *(const uint2*)(gc + (size_t)csr_src[e + 2] * 64);
        uint2 v3 = *(const uint2*)(gc + (size_t)csr_src[e + 3] * 64);
        acc[0] += (bf_lo(v0.x) + bf_lo(v1.x)) + (bf_lo(v2.x) + bf_lo(v3.x));
        acc[1] += (bf_hi(v0.x) + bf_hi(v1.x)) + (bf_hi(v2.x) + bf_hi(v3.x));
        acc[2] += (bf_lo(v0.y) + bf_lo(v1.y)) + (bf_lo(v2.y) + bf_lo(v3.y));
        acc[3] += (bf_hi(v0.y) + bf_hi(v1.y)) + (bf_hi(v2.y) + bf_hi(v3.y));
    }
    for (; e < s1; ++e) {
        uint2 v0 = *(const uint2*)(gc + (size_t)csr_src[e] * 64);
        acc[0] += bf_lo(v0.x); acc[1] += bf_hi(v0.x);
        acc[2] += bf_lo(v0.y); acc[3] += bf_hi(v0.y);
    }
    float inv = 1.0f / (float)max(s1 - s0, 1);
    uint2 rv = *(const uint2*)(r + (size_t)n * 64 + lane * 4);
    float4 o;
    o.x = fmaf(acc[0], inv, bf_lo(rv.x));
    o.y = fmaf(acc[1], inv, bf_hi(rv.x));
    o.z = fmaf(acc[2], inv, bf_lo(rv.y));
    o.w = fmaf(acc[3], inv, bf_hi(rv.y));
    *(float4*)(out + (size_t)n * 64 + lane * 4) = o;
}

// ---------------------------------------------------------------------------

extern "C" void kernel_launch(void* const* d_in, const int* in_sizes, int n_in,
                              void* d_out, int out_size, void* d_ws, size_t ws_size,
                              hipStream_t stream) {
    const float* x    = (const float*)d_in[0];
    const int*   ei   = (const int*)d_in[1];
    const float* W1_l = (const float*)d_in[2];
    const float* b1   = (const float*)d_in[3];
    const float* W1_r = (const float*)d_in[4];
    const float* W2_l = (const float*)d_in[5];
    const float* b2   = (const float*)d_in[6];
    const float* W2_r = (const float*)d_in[7];

    const int N = in_sizes[0] / 128;   // 50000
    const int E = in_sizes[1] / 2;     // 800000
    const int* e_src = ei;
    const int* e_dst = ei + E;

    // ---- workspace layout ----
    char* ws = (char*)d_ws;
    auto align256 = [](size_t v) { return (v + 255) & ~(size_t)255; };
    size_t off = 0;
    int* row_start = (int*)(ws + off); off += align256((size_t)(N + 1) * 4);
    int* bsum      = (int*)(ws + off); off += align256(1024);
    int* hist      = (int*)(ws + off); off += align256((size_t)NRANGE * NSTRIPE * PACKED_W * 4);
    int* cur       = (int*)(ws + off); off += align256((size_t)NRANGE * NSTRIPE * RANGE_W * 4);
    int* csr_src   = (int*)(ws + off); off += align256((size_t)E * 4);
    unsigned short* h_bf  = (unsigned short*)(ws + off); off += align256((size_t)N * 128 * 2);
    unsigned short* pg_bf = (unsigned short*)(ws + off); off += align256((size_t)N * 128 * 2);
    unsigned short* qr_bf = (unsigned short*)(ws + off); off += align256((size_t)N * 128 * 2);
    unsigned short* wt1l  = (unsigned short*)(ws + off); off += align256(128 * 128 * 2);
    unsigned short* wt1r  = (unsigned short*)(ws + off); off += align256(128 * 128 * 2);
    unsigned short* wt2l  = (unsigned short*)(ws + off); off += align256(128 * 64 * 2);
    unsigned short* wt2r  = (unsigned short*)(ws + off); off += align256(128 * 64 * 2);
    float* out = (float*)d_out;

    const int nb = (N + 255) / 256;
    const int nGemmWg = (N + 63) / 64;

    // ---- weight prep ----
    wt_all_kernel<<<(16384 + 8192 + 255) / 256, 256, 0, stream>>>(
        W1_l, W1_r, W2_l, W2_r, wt1l, wt1r, wt2l, wt2r);
    // ---- GEMM-1 (p, q+b1) overlapped with packed histogram ----
    gemm1_hist_kernel<<<nGemmWg + NRANGE * NSTRIPE, 256, 0, stream>>>(
        x, wt1l, wt1r, b1, pg_bf, qr_bf, N, e_dst, hist, E, N, nGemmWg);
    // ---- CSR finish (no global atomics) ----
    scan16_kernel<<<nb, 256, 0, stream>>>(hist, row_start, bsum, N);
    add_off_base_kernel<<<nb, 256, 0, stream>>>(row_start, bsum, hist, cur, N, E);
    scatter_lds_kernel<<<NRANGE * NSTRIPE, 256, 0, stream>>>(e_src, e_dst, cur,
                                                             csr_src, E, N);
    // ---- layer 1 aggregate ----
    agg1_kernel<<<(N + 15) / 16, 256, 0, stream>>>(pg_bf, qr_bf, row_start,
                                                   csr_src, h_bf, N);
    // ---- layer 2 ----
    mfma_dual_gemm2<<<(N + 63) / 64, 256, 0, stream>>>(h_bf, wt2l, wt2r, b2,
                                                       pg_bf, qr_bf, N);
    agg2_kernel<<<(N + 15) / 16, 256, 0, stream>>>(pg_bf, qr_bf, row_start,
                                                   csr_src, out, N);
}